// Round 2
// baseline (219.350 us; speedup 1.0000x reference)
//
#include <hip/hip_runtime.h>
#include <hip/hip_bf16.h>

typedef __bf16 bf16;
typedef __bf16 bf16x8 __attribute__((ext_vector_type(8)));
typedef __bf16 bf16x4 __attribute__((ext_vector_type(4)));
typedef float f32x4 __attribute__((ext_vector_type(4)));
typedef unsigned short u16;
typedef unsigned short u16x8 __attribute__((ext_vector_type(8)));

constexpr int kHW = 1024;   // 32*32
constexpr int kC  = 512;
constexpr int kB  = 16;
constexpr int kCPG = 16;    // channels per group (512/32)

__device__ inline float wave_sum(float v) {
#pragma unroll
    for (int o = 32; o; o >>= 1) v += __shfl_xor(v, o, 64);
    return v;
}
__device__ inline float wave_max(float v) {
#pragma unroll
    for (int o = 32; o; o >>= 1) v = fmaxf(v, __shfl_xor(v, o, 64));
    return v;
}

// async global -> LDS, 16B per lane, wave-uniform LDS base
__device__ inline void gload_lds16(const void* g, void* l) {
    __builtin_amdgcn_global_load_lds(
        (const __attribute__((address_space(1))) void*)g,
        (__attribute__((address_space(3))) void*)l, 16, 0, 0);
}

// ---------------- weight f32 -> bf16 ----------------
__global__ __launch_bounds__(256) void wconv_kernel(
    const float* __restrict__ wq, const float* __restrict__ wk,
    const float* __restrict__ wv, const float* __restrict__ wp,
    bf16* __restrict__ dst)
{
    int i = blockIdx.x * 256 + threadIdx.x;   // grid covers 262144
    dst[i]            = (bf16)wq[i];
    dst[262144 + i]   = (bf16)wk[i];
    dst[2*262144 + i] = (bf16)wv[i];
    dst[3*262144 + i] = (bf16)wp[i];
}

// ---------------- GroupNorm -> transposed bf16 [b][hw][c] ----------------
__global__ __launch_bounds__(256) void gn_kernel(
    const float* __restrict__ x, const float* __restrict__ scale,
    const float* __restrict__ bias, bf16* __restrict__ outT)
{
    int blk = blockIdx.x;            // b*32 + g
    int b = blk >> 5, g = blk & 31;
    int c0 = g * kCPG;
    const float* xg = x + ((size_t)b * kC + c0) * kHW;   // contiguous [16][1024]

    float s = 0.f, s2 = 0.f;
    const float4* xg4 = reinterpret_cast<const float4*>(xg);
#pragma unroll
    for (int i = 0; i < 16; ++i) {
        float4 v = xg4[threadIdx.x + i * 256];
        s  += v.x + v.y + v.z + v.w;
        s2 += v.x*v.x + v.y*v.y + v.z*v.z + v.w*v.w;
    }
    s = wave_sum(s); s2 = wave_sum(s2);
    __shared__ float red[8];
    int lane = threadIdx.x & 63, wid = threadIdx.x >> 6;
    if (!lane) { red[wid] = s; red[4 + wid] = s2; }
    __syncthreads();
    float ts = red[0] + red[1] + red[2] + red[3];
    float t2 = red[4] + red[5] + red[6] + red[7];
    float mean = ts * (1.f / 16384.f);
    float var  = t2 * (1.f / 16384.f) - mean * mean;
    float inv  = rsqrtf(var + 1e-6f);

    // pass 2: ci-fast so transposed writes are 32B-contiguous per 16 lanes
    int ci = threadIdx.x & 15;
    float a  = inv * scale[c0 + ci];
    float bb = bias[c0 + ci] - mean * a;
#pragma unroll
    for (int i = 0; i < 64; ++i) {
        int f = threadIdx.x + i * 256;
        int sp = f >> 4;
        float v = xg[ci * kHW + sp];          // L1/L2-hot from pass 1
        outT[((size_t)b * kHW + sp) * kC + c0 + ci] = (bf16)(v * a + bb);
    }
}

// ---------------- row softmax, f32 in, bf16 out (in-place, ld 2048) -------
__global__ __launch_bounds__(256) void softmax_kernel(float* __restrict__ S)
{
    size_t row = blockIdx.x;                    // b*1024 + i
    float* Srow = S + row * 1024;
    bf16*  Prow = reinterpret_cast<bf16*>(S) + row * 2048;
    int t = threadIdx.x;
    float4 v = reinterpret_cast<const float4*>(Srow)[t];
    float m = fmaxf(fmaxf(v.x, v.y), fmaxf(v.z, v.w));
    m = wave_max(m);
    __shared__ float redm[4], reds[4];
    int lane = t & 63, wid = t >> 6;
    if (!lane) redm[wid] = m;
    __syncthreads();
    m = fmaxf(fmaxf(redm[0], redm[1]), fmaxf(redm[2], redm[3]));
    float e0 = __expf(v.x - m), e1 = __expf(v.y - m);
    float e2 = __expf(v.z - m), e3 = __expf(v.w - m);
    float s = wave_sum(e0 + e1 + e2 + e3);
    if (!lane) reds[wid] = s;
    __syncthreads();
    s = reds[0] + reds[1] + reds[2] + reds[3];
    float r = 1.f / s;
    bf16x4 p = { (bf16)(e0 * r), (bf16)(e1 * r), (bf16)(e2 * r), (bf16)(e3 * r) };
    reinterpret_cast<bf16x4*>(Prow)[t] = p;     // row fully read before write
}

// ---------------- generic NT GEMM: C[M][N] = alpha*A[M][K]·B[N][K]^T ------
// m97 structure: 128x128 tile, BK=64, linear LDS + global_load_lds width=16.
// BIAS: 0 none, 1 per-row(M), 2 per-col(N). RESID adds f32 residual.
template <int BIAS, bool RESID, typename OUT_T>
__global__ __launch_bounds__(256) void gemm_nt(
    const bf16* __restrict__ Ag, size_t sA, int lda,
    const bf16* __restrict__ Bg, size_t sB, int ldb,
    OUT_T* __restrict__ Cg, size_t sC, int ldc,
    const float* __restrict__ bias,
    const float* __restrict__ resid, size_t sR,
    int K, float alpha)
{
    __shared__ u16 As[128][64];   // linear: global_load_lds writes lane*16B
    __shared__ u16 Bs[128][64];
    int bz = blockIdx.z;
    Ag += bz * sA; Bg += bz * sB; Cg += bz * sC;
    int brow = blockIdx.y * 128, bcol = blockIdx.x * 128;
    int t = threadIdx.x;
    int lane = t & 63, w = t >> 6;
    int wm = w >> 1, wn = w & 1;

    f32x4 acc[4][4] = {};
    const u16* Au = reinterpret_cast<const u16*>(Ag);
    const u16* Bu = reinterpret_cast<const u16*>(Bg);

    // wave w stages rows [w*32, w*32+32): 4 instrs of 8 rows x 64 cols each.
    // lane l -> row (l>>3), col chunk (l&7)*8  == LDS linear order.
    const u16* Asrc = Au + (size_t)(brow + w * 32 + (lane >> 3)) * lda + (lane & 7) * 8;
    const u16* Bsrc = Bu + (size_t)(bcol + w * 32 + (lane >> 3)) * ldb + (lane & 7) * 8;
    u16* AsBase = &As[w * 32][0];
    u16* BsBase = &Bs[w * 32][0];

    for (int k0 = 0; k0 < K; k0 += 64) {
#pragma unroll
        for (int p = 0; p < 4; ++p) {
            gload_lds16(Asrc + (size_t)p * 8 * lda + k0, AsBase + p * 8 * 64);
            gload_lds16(Bsrc + (size_t)p * 8 * ldb + k0, BsBase + p * 8 * 64);
        }
        __syncthreads();   // compiler drains vmcnt before s_barrier
#pragma unroll
        for (int kk = 0; kk < 64; kk += 32) {
            bf16x8 a[4], bfr[4];
#pragma unroll
            for (int m = 0; m < 4; ++m)
                a[m] = *reinterpret_cast<const bf16x8*>(&As[wm*64 + m*16 + (lane & 15)][kk + (lane >> 4) * 8]);
#pragma unroll
            for (int n = 0; n < 4; ++n)
                bfr[n] = *reinterpret_cast<const bf16x8*>(&Bs[wn*64 + n*16 + (lane & 15)][kk + (lane >> 4) * 8]);
#pragma unroll
            for (int m = 0; m < 4; ++m)
#pragma unroll
                for (int n = 0; n < 4; ++n)
                    acc[m][n] = __builtin_amdgcn_mfma_f32_16x16x32_bf16(a[m], bfr[n], acc[m][n], 0, 0, 0);
        }
        __syncthreads();
    }

    int cr = lane >> 4, cc = lane & 15;
#pragma unroll
    for (int m = 0; m < 4; ++m) {
#pragma unroll
        for (int n = 0; n < 4; ++n) {
#pragma unroll
            for (int r = 0; r < 4; ++r) {
                int grow = brow + wm*64 + m*16 + cr*4 + r;
                int gcol = bcol + wn*64 + n*16 + cc;
                float vv = acc[m][n][r] * alpha;
                if (BIAS == 1) vv += bias[grow];
                if (BIAS == 2) vv += bias[gcol];
                if (RESID)     vv += resid[bz * sR + (size_t)grow * ldc + gcol];
                Cg[(size_t)grow * ldc + gcol] = (OUT_T)vv;
            }
        }
    }
}

extern "C" void kernel_launch(void* const* d_in, const int* in_sizes, int n_in,
                              void* d_out, int out_size, void* d_ws, size_t ws_size,
                              hipStream_t stream)
{
    const float* x   = (const float*)d_in[0];
    const float* y   = (const float*)d_in[1];
    const float* ns  = (const float*)d_in[2];
    const float* nb  = (const float*)d_in[3];
    const float* n1s = (const float*)d_in[4];
    const float* n1b = (const float*)d_in[5];
    const float* wq  = (const float*)d_in[6];
    const float* bq  = (const float*)d_in[7];
    const float* wk  = (const float*)d_in[8];
    const float* bk  = (const float*)d_in[9];
    const float* wv  = (const float*)d_in[10];
    const float* bv  = (const float*)d_in[11];
    const float* wp  = (const float*)d_in[12];
    const float* bp  = (const float*)d_in[13];
    float* out = (float*)d_out;

    char* ws = (char*)d_ws;
    bf16* wbf  = (bf16*)ws;                      // 4 x 512*512 bf16 = 2 MB
    bf16* wq_b = wbf;
    bf16* wk_b = wbf + 262144;
    bf16* wv_b = wbf + 2 * 262144;
    bf16* wp_b = wbf + 3 * 262144;
    bf16* hnT = (bf16*)(ws + 2097152);           // [b][hw][c] bf16
    bf16* ynT = hnT + 8388608;
    bf16* qT  = ynT + 8388608;                   // [b][hw][c]
    bf16* kT  = qT  + 8388608;                   // [b][hw][c]
    bf16* v   = kT  + 8388608;                   // [b][c][hw]
    bf16* aoT = v   + 8388608;                   // [b][hw][c]
    float* S  = (float*)(ws + 102760448);        // [b][1024][1024] f32; P aliased
    bf16*  P  = (bf16*)S;                        // ld = 2048 within S rows

    const size_t sBC = (size_t)kHW * kC;         // 524288 elements per batch
    const float scl = 0.044194173824159216f;     // 512^-0.5

    wconv_kernel<<<1024, 256, 0, stream>>>(wq, wk, wv, wp, wbf);
    gn_kernel<<<512, 256, 0, stream>>>(x, ns,  nb,  hnT);
    gn_kernel<<<512, 256, 0, stream>>>(y, n1s, n1b, ynT);

    // q_T[i][o] = yn_T[i][c] · wq[o][c] + bq[o]
    gemm_nt<2, false, bf16><<<dim3(4, 8, kB), 256, 0, stream>>>(
        ynT, sBC, 512, wq_b, 0, 512, qT, sBC, 512, bq, nullptr, 0, 512, 1.f);
    // k_T[j][o] = hn_T[j][c] · wk[o][c] + bk[o]
    gemm_nt<2, false, bf16><<<dim3(4, 8, kB), 256, 0, stream>>>(
        hnT, sBC, 512, wk_b, 0, 512, kT, sBC, 512, bk, nullptr, 0, 512, 1.f);
    // v[o][n] = wv[o][c] · hn_T[n][c] + bv[o]
    gemm_nt<1, false, bf16><<<dim3(8, 4, kB), 256, 0, stream>>>(
        wv_b, 0, 512, hnT, sBC, 512, v, sBC, 1024, bv, nullptr, 0, 512, 1.f);
    // S[i][j] = scl * q_T[i][c] · k_T[j][c]
    gemm_nt<0, false, float><<<dim3(8, 8, kB), 256, 0, stream>>>(
        qT, sBC, 512, kT, sBC, 512, S, (size_t)1048576, 1024,
        nullptr, nullptr, 0, 512, scl);
    softmax_kernel<<<16384, 256, 0, stream>>>(S);
    // ao_T[i][c] = P[i][j] · v[c][j]
    gemm_nt<0, false, bf16><<<dim3(4, 8, kB), 256, 0, stream>>>(
        P, (size_t)2097152, 2048, v, sBC, 1024, aoT, sBC, 512,
        nullptr, nullptr, 0, 1024, 1.f);
    // out[o][n] = wp[o][c] · ao_T[n][c] + bp[o] + x[o][n]
    gemm_nt<1, true, float><<<dim3(8, 4, kB), 256, 0, stream>>>(
        wp_b, 0, 512, aoT, sBC, 512, out, sBC, 1024, bp, x, sBC, 512, 1.f);
}

// Round 3
// 200.060 us; speedup vs baseline: 1.0964x; 1.0964x over previous
//
#include <hip/hip_runtime.h>
#include <hip/hip_bf16.h>

typedef __bf16 bf16;
typedef __bf16 bf16x8 __attribute__((ext_vector_type(8)));
typedef __bf16 bf16x4 __attribute__((ext_vector_type(4)));
typedef float f32x4 __attribute__((ext_vector_type(4)));
typedef unsigned short u16;
typedef unsigned short u16x8 __attribute__((ext_vector_type(8)));

constexpr int kHW = 1024;   // 32*32
constexpr int kC  = 512;
constexpr int kB  = 16;
constexpr int kCPG = 16;    // channels per group (512/32)

__device__ inline float wave_sum(float v) {
#pragma unroll
    for (int o = 32; o; o >>= 1) v += __shfl_xor(v, o, 64);
    return v;
}
__device__ inline float wave_max(float v) {
#pragma unroll
    for (int o = 32; o; o >>= 1) v = fmaxf(v, __shfl_xor(v, o, 64));
    return v;
}

// ---------------- weight f32 -> bf16 ----------------
__global__ __launch_bounds__(256) void wconv_kernel(
    const float* __restrict__ wq, const float* __restrict__ wk,
    const float* __restrict__ wv, const float* __restrict__ wp,
    bf16* __restrict__ dst)
{
    int i = blockIdx.x * 256 + threadIdx.x;   // grid covers 262144
    dst[i]            = (bf16)wq[i];
    dst[262144 + i]   = (bf16)wk[i];
    dst[2*262144 + i] = (bf16)wv[i];
    dst[3*262144 + i] = (bf16)wp[i];
}

// ---------------- GroupNorm -> transposed bf16 [b][hw][c] ----------------
__global__ __launch_bounds__(256) void gn_kernel(
    const float* __restrict__ x, const float* __restrict__ scale,
    const float* __restrict__ bias, bf16* __restrict__ outT)
{
    int blk = blockIdx.x;            // b*32 + g
    int b = blk >> 5, g = blk & 31;
    int c0 = g * kCPG;
    const float* xg = x + ((size_t)b * kC + c0) * kHW;   // contiguous [16][1024]

    float s = 0.f, s2 = 0.f;
    const float4* xg4 = reinterpret_cast<const float4*>(xg);
#pragma unroll
    for (int i = 0; i < 16; ++i) {
        float4 v = xg4[threadIdx.x + i * 256];
        s  += v.x + v.y + v.z + v.w;
        s2 += v.x*v.x + v.y*v.y + v.z*v.z + v.w*v.w;
    }
    s = wave_sum(s); s2 = wave_sum(s2);
    __shared__ float red[8];
    int lane = threadIdx.x & 63, wid = threadIdx.x >> 6;
    if (!lane) { red[wid] = s; red[4 + wid] = s2; }
    __syncthreads();
    float ts = red[0] + red[1] + red[2] + red[3];
    float t2 = red[4] + red[5] + red[6] + red[7];
    float mean = ts * (1.f / 16384.f);
    float var  = t2 * (1.f / 16384.f) - mean * mean;
    float inv  = rsqrtf(var + 1e-6f);

    // pass 2: ci-fast so transposed writes are 32B-contiguous per 16 lanes
    int ci = threadIdx.x & 15;
    float a  = inv * scale[c0 + ci];
    float bb = bias[c0 + ci] - mean * a;
#pragma unroll
    for (int i = 0; i < 64; ++i) {
        int f = threadIdx.x + i * 256;
        int sp = f >> 4;
        float v = xg[ci * kHW + sp];          // L1/L2-hot from pass 1
        outT[((size_t)b * kHW + sp) * kC + c0 + ci] = (bf16)(v * a + bb);
    }
}

// ---------------- generic NT GEMM: C[M][N] = alpha*A[M][K]·B[N][K]^T ------
// Padded reg-staged LDS (round-1 structure, ~free 2-way conflicts).
// BIAS: 0 none, 1 per-row(M), 2 per-col(N). RESID adds f32 residual.
// STATS: emit per-(row, col-block) softmax partials (max, sumexp) for PV.
// SWZ: 1D launch, bijective XCD swizzle so each XCD owns whole batches.
template <int BIAS, bool RESID, typename OUT_T, bool STATS, bool SWZ>
__global__ __launch_bounds__(256) void gemm_nt(
    const bf16* __restrict__ Ag, size_t sA, int lda,
    const bf16* __restrict__ Bg, size_t sB, int ldb,
    OUT_T* __restrict__ Cg, size_t sC, int ldc,
    const float* __restrict__ bias,
    const float* __restrict__ resid, size_t sR,
    int K, float alpha,
    float* __restrict__ statsOut, int nbx, int nby)
{
    __shared__ u16 As[128][72];   // +8 pad: row stride 144B -> <=2-way banks
    __shared__ u16 Bs[128][72];

    int bx, by, bz;
    if (SWZ) {
        int nwg = gridDim.x;
        int qq = nwg >> 3;                       // nwg % 8 == 0 guaranteed
        int swz = (blockIdx.x & 7) * qq + (blockIdx.x >> 3);
        int per = nbx * nby;
        bz = swz / per;
        int remb = swz % per;
        by = remb / nbx; bx = remb % nbx;
    } else {
        bx = blockIdx.x; by = blockIdx.y; bz = blockIdx.z;
    }

    Ag += bz * sA; Bg += bz * sB; Cg += bz * sC;
    int brow = by * 128, bcol = bx * 128;
    int t = threadIdx.x;
    int lane = t & 63, w = t >> 6;
    int wm = w >> 1, wn = w & 1;

    f32x4 acc[4][4] = {};
    const u16* Au = reinterpret_cast<const u16*>(Ag);
    const u16* Bu = reinterpret_cast<const u16*>(Bg);

    for (int k0 = 0; k0 < K; k0 += 64) {
#pragma unroll
        for (int p = 0; p < 4; ++p) {
            int idx = p * 256 + t;        // 1024 chunk positions
            int row = idx >> 3, ch = idx & 7;
            u16x8 va = *reinterpret_cast<const u16x8*>(Au + (size_t)(brow + row) * lda + k0 + ch * 8);
            *reinterpret_cast<u16x8*>(&As[row][ch * 8]) = va;
            u16x8 vb = *reinterpret_cast<const u16x8*>(Bu + (size_t)(bcol + row) * ldb + k0 + ch * 8);
            *reinterpret_cast<u16x8*>(&Bs[row][ch * 8]) = vb;
        }
        __syncthreads();
#pragma unroll
        for (int kk = 0; kk < 64; kk += 32) {
            bf16x8 a[4], bfr[4];
#pragma unroll
            for (int m = 0; m < 4; ++m)
                a[m] = *reinterpret_cast<const bf16x8*>(&As[wm*64 + m*16 + (lane & 15)][kk + (lane >> 4) * 8]);
#pragma unroll
            for (int n = 0; n < 4; ++n)
                bfr[n] = *reinterpret_cast<const bf16x8*>(&Bs[wn*64 + n*16 + (lane & 15)][kk + (lane >> 4) * 8]);
#pragma unroll
            for (int m = 0; m < 4; ++m)
#pragma unroll
                for (int n = 0; n < 4; ++n)
                    acc[m][n] = __builtin_amdgcn_mfma_f32_16x16x32_bf16(a[m], bfr[n], acc[m][n], 0, 0, 0);
        }
        __syncthreads();
    }

    // scale once so stats + write see the same values
#pragma unroll
    for (int m = 0; m < 4; ++m)
#pragma unroll
        for (int n = 0; n < 4; ++n)
#pragma unroll
            for (int r = 0; r < 4; ++r)
                acc[m][n][r] *= alpha;

    int cr = lane >> 4, cc = lane & 15;

    if constexpr (STATS) {
        __shared__ float sred[2][2][128];   // [max|sum][wn][local row]
        float rmax[4][4];
#pragma unroll
        for (int m = 0; m < 4; ++m)
#pragma unroll
            for (int r = 0; r < 4; ++r) {
                float v_ = fmaxf(fmaxf(acc[m][0][r], acc[m][1][r]),
                                 fmaxf(acc[m][2][r], acc[m][3][r]));
                v_ = fmaxf(v_, __shfl_xor(v_, 1, 64));
                v_ = fmaxf(v_, __shfl_xor(v_, 2, 64));
                v_ = fmaxf(v_, __shfl_xor(v_, 4, 64));
                v_ = fmaxf(v_, __shfl_xor(v_, 8, 64));
                rmax[m][r] = v_;
            }
        if (cc == 0)
#pragma unroll
            for (int m = 0; m < 4; ++m)
#pragma unroll
                for (int r = 0; r < 4; ++r)
                    sred[0][wn][wm*64 + m*16 + cr*4 + r] = rmax[m][r];
        __syncthreads();
#pragma unroll
        for (int m = 0; m < 4; ++m)
#pragma unroll
            for (int r = 0; r < 4; ++r) {
                int lr = wm*64 + m*16 + cr*4 + r;
                rmax[m][r] = fmaxf(sred[0][0][lr], sred[0][1][lr]);
            }
        float rsum[4][4];
#pragma unroll
        for (int m = 0; m < 4; ++m)
#pragma unroll
            for (int r = 0; r < 4; ++r) {
                float s_ = 0.f;
#pragma unroll
                for (int n = 0; n < 4; ++n)
                    s_ += __expf(acc[m][n][r] - rmax[m][r]);
                s_ += __shfl_xor(s_, 1, 64);
                s_ += __shfl_xor(s_, 2, 64);
                s_ += __shfl_xor(s_, 4, 64);
                s_ += __shfl_xor(s_, 8, 64);
                rsum[m][r] = s_;
            }
        if (cc == 0)
#pragma unroll
            for (int m = 0; m < 4; ++m)
#pragma unroll
                for (int r = 0; r < 4; ++r)
                    sred[1][wn][wm*64 + m*16 + cr*4 + r] = rsum[m][r];
        __syncthreads();
        if (t < 128) {
            float M = fmaxf(sred[0][0][t], sred[0][1][t]);
            float L = sred[1][0][t] + sred[1][1][t];
            size_t off = ((size_t)(bz * 1024 + brow + t)) * 16 + bx * 2;
            statsOut[off]     = M;
            statsOut[off + 1] = L;
        }
    }

#pragma unroll
    for (int m = 0; m < 4; ++m) {
#pragma unroll
        for (int n = 0; n < 4; ++n) {
#pragma unroll
            for (int r = 0; r < 4; ++r) {
                int grow = brow + wm*64 + m*16 + cr*4 + r;
                int gcol = bcol + wn*64 + n*16 + cc;
                float vv = acc[m][n][r];
                if (BIAS == 1) vv += bias[grow];
                if (BIAS == 2) vv += bias[gcol];
                if (RESID)     vv += resid[bz * sR + (size_t)grow * ldc + gcol];
                Cg[(size_t)grow * ldc + gcol] = (OUT_T)vv;
            }
        }
    }
}

// ---------------- PV with fused softmax -----------------------------------
// O[i][c] = (1/L_i) * sum_j exp(S[i][j]-M_i) * V[c][j]; stats combined in
// prologue; exp applied during A-staging; divide by L in epilogue.
__global__ __launch_bounds__(256) void gemm_pv(
    const float* __restrict__ S, const float* __restrict__ stats,
    const bf16* __restrict__ V, bf16* __restrict__ O,
    int nbx, int nby)
{
    __shared__ u16 As[128][72];
    __shared__ u16 Bs[128][72];
    __shared__ float Ml[128], Ll[128];

    int nwg = gridDim.x;
    int qq = nwg >> 3;
    int swz = (blockIdx.x & 7) * qq + (blockIdx.x >> 3);
    int per = nbx * nby;
    int bz = swz / per;
    int remb = swz % per;
    int by = remb / nbx, bx = remb % nbx;
    int brow = by * 128, bcol = bx * 128;
    int t = threadIdx.x;
    int lane = t & 63, w = t >> 6;
    int wm = w >> 1, wn = w & 1;

    if (t < 128) {
        const float* st = stats + ((size_t)(bz * 1024 + brow + t)) * 16;
        float M = st[0];
#pragma unroll
        for (int k = 1; k < 8; ++k) M = fmaxf(M, st[2*k]);
        float L = 0.f;
#pragma unroll
        for (int k = 0; k < 8; ++k) L += st[2*k + 1] * __expf(st[2*k] - M);
        Ml[t] = M; Ll[t] = L;
    }
    __syncthreads();
    float am[8];
#pragma unroll
    for (int p = 0; p < 8; ++p) am[p] = Ml[p * 16 + (t >> 4)];

    const float* Sb = S + (size_t)bz * 1048576 + (size_t)brow * 1024;
    const u16*   Vb = reinterpret_cast<const u16*>(V + (size_t)bz * 524288) + (size_t)bcol * 1024;

    f32x4 acc[4][4] = {};
    for (int k0 = 0; k0 < 1024; k0 += 64) {
#pragma unroll
        for (int p = 0; p < 8; ++p) {          // A: 128 rows x 16 float4 chunks
            int idx = p * 256 + t;
            int row = idx >> 4, ch = idx & 15;
            float4 sv = *reinterpret_cast<const float4*>(Sb + (size_t)row * 1024 + k0 + ch * 4);
            bf16x4 pb;
            pb[0] = (bf16)__expf(sv.x - am[p]);
            pb[1] = (bf16)__expf(sv.y - am[p]);
            pb[2] = (bf16)__expf(sv.z - am[p]);
            pb[3] = (bf16)__expf(sv.w - am[p]);
            *reinterpret_cast<bf16x4*>(&As[row][ch * 4]) = pb;
        }
#pragma unroll
        for (int p = 0; p < 4; ++p) {          // B: 128 rows x 8 u16x8 chunks
            int idx = p * 256 + t;
            int row = idx >> 3, ch = idx & 7;
            *reinterpret_cast<u16x8*>(&Bs[row][ch * 8]) =
                *reinterpret_cast<const u16x8*>(Vb + (size_t)row * 1024 + k0 + ch * 8);
        }
        __syncthreads();
#pragma unroll
        for (int kk = 0; kk < 64; kk += 32) {
            bf16x8 a[4], bfr[4];
#pragma unroll
            for (int m = 0; m < 4; ++m)
                a[m] = *reinterpret_cast<const bf16x8*>(&As[wm*64 + m*16 + (lane & 15)][kk + (lane >> 4) * 8]);
#pragma unroll
            for (int n = 0; n < 4; ++n)
                bfr[n] = *reinterpret_cast<const bf16x8*>(&Bs[wn*64 + n*16 + (lane & 15)][kk + (lane >> 4) * 8]);
#pragma unroll
            for (int m = 0; m < 4; ++m)
#pragma unroll
                for (int n = 0; n < 4; ++n)
                    acc[m][n] = __builtin_amdgcn_mfma_f32_16x16x32_bf16(a[m], bfr[n], acc[m][n], 0, 0, 0);
        }
        __syncthreads();
    }

    int cr = lane >> 4, cc = lane & 15;
#pragma unroll
    for (int m = 0; m < 4; ++m) {
#pragma unroll
        for (int r = 0; r < 4; ++r) {
            int lr = wm*64 + m*16 + cr*4 + r;
            float linv = 1.0f / Ll[lr];
#pragma unroll
            for (int n = 0; n < 4; ++n) {
                int gcol = bcol + wn*64 + n*16 + cc;
                O[(size_t)bz * 524288 + (size_t)(brow + lr) * 512 + gcol] =
                    (bf16)(acc[m][n][r] * linv);
            }
        }
    }
}

extern "C" void kernel_launch(void* const* d_in, const int* in_sizes, int n_in,
                              void* d_out, int out_size, void* d_ws, size_t ws_size,
                              hipStream_t stream)
{
    const float* x   = (const float*)d_in[0];
    const float* y   = (const float*)d_in[1];
    const float* ns  = (const float*)d_in[2];
    const float* nb  = (const float*)d_in[3];
    const float* n1s = (const float*)d_in[4];
    const float* n1b = (const float*)d_in[5];
    const float* wq  = (const float*)d_in[6];
    const float* bq  = (const float*)d_in[7];
    const float* wk  = (const float*)d_in[8];
    const float* bk  = (const float*)d_in[9];
    const float* wv  = (const float*)d_in[10];
    const float* bv  = (const float*)d_in[11];
    const float* wp  = (const float*)d_in[12];
    const float* bp  = (const float*)d_in[13];
    float* out = (float*)d_out;

    char* ws = (char*)d_ws;
    bf16* wbf  = (bf16*)ws;                      // 4 x 512*512 bf16 = 2 MB
    bf16* wq_b = wbf;
    bf16* wk_b = wbf + 262144;
    bf16* wv_b = wbf + 2 * 262144;
    bf16* wp_b = wbf + 3 * 262144;
    bf16* hnT = (bf16*)(ws + 2097152);           // [b][hw][c]; region reused for stats later
    bf16* ynT = hnT + 8388608;
    bf16* qT  = ynT + 8388608;                   // [b][hw][c]
    bf16* kT  = qT  + 8388608;                   // [b][hw][c]
    bf16* v   = kT  + 8388608;                   // [b][c][hw]
    bf16* aoT = v   + 8388608;                   // [b][hw][c]
    float* S  = (float*)(ws + 102760448);        // [b][1024][1024] f32
    float* stats = (float*)hnT;                  // [b][1024][8][2] f32 = 1 MB; hnT dead by QK^T

    const size_t sBC = (size_t)kHW * kC;         // 524288 elements per batch
    const float scl = 0.044194173824159216f;     // 512^-0.5

    wconv_kernel<<<1024, 256, 0, stream>>>(wq, wk, wv, wp, wbf);
    gn_kernel<<<512, 256, 0, stream>>>(x, ns,  nb,  hnT);
    gn_kernel<<<512, 256, 0, stream>>>(y, n1s, n1b, ynT);

    // q conv, merged M = b*hw = 16384: q_T[i][o] = yn_T[i][c]·wq[o][c] + bq[o]
    gemm_nt<2, false, bf16, false, false><<<dim3(4, 128, 1), 256, 0, stream>>>(
        ynT, 0, 512, wq_b, 0, 512, qT, 0, 512, bq, nullptr, 0, 512, 1.f,
        nullptr, 0, 0);
    // k conv, merged M = 16384
    gemm_nt<2, false, bf16, false, false><<<dim3(4, 128, 1), 256, 0, stream>>>(
        hnT, 0, 512, wk_b, 0, 512, kT, 0, 512, bk, nullptr, 0, 512, 1.f,
        nullptr, 0, 0);
    // v conv per batch (needs [b][c][hw] output): v[o][n] = wv[o][c]·hn_T[n][c] + bv[o]
    gemm_nt<1, false, bf16, false, true><<<512, 256, 0, stream>>>(
        wv_b, 0, 512, hnT, sBC, 512, v, sBC, 1024, bv, nullptr, 0, 512, 1.f,
        nullptr, 8, 4);
    // S[i][j] = scl * q_T[i][c]·k_T[j][c]  (+ per-block row stats)
    gemm_nt<0, false, float, true, true><<<1024, 256, 0, stream>>>(
        qT, sBC, 512, kT, sBC, 512, S, (size_t)1048576, 1024,
        nullptr, nullptr, 0, 512, scl, stats, 8, 8);
    // fused softmax + PV: ao_T[i][c]
    gemm_pv<<<512, 256, 0, stream>>>(S, stats, v, aoT, 4, 8);
    // out[o][n] = wp[o][c]·ao_T[n][c] + bp[o] + x[o][n]
    gemm_nt<1, true, float, false, true><<<512, 256, 0, stream>>>(
        wp_b, 0, 512, aoT, sBC, 512, out, sBC, 1024, bp, x, sBC, 512, 1.f,
        nullptr, 8, 4);
}

// Round 4
// 198.369 us; speedup vs baseline: 1.1058x; 1.0085x over previous
//
#include <hip/hip_runtime.h>
#include <hip/hip_bf16.h>

typedef __bf16 bf16;
typedef __bf16 bf16x8 __attribute__((ext_vector_type(8)));
typedef float f32x4 __attribute__((ext_vector_type(4)));
typedef unsigned short u16;

constexpr int kHW = 1024;
constexpr int kC  = 512;
constexpr int kCPG = 16;

__device__ inline float wave_sum(float v) {
#pragma unroll
    for (int o = 32; o; o >>= 1) v += __shfl_xor(v, o, 64);
    return v;
}

__device__ inline void gload_lds16(const void* g, void* l) {
    __builtin_amdgcn_global_load_lds(
        (const __attribute__((address_space(1))) void*)g,
        (__attribute__((address_space(3))) void*)l, 16, 0, 0);
}

#define VMCNT(n) asm volatile("s_waitcnt vmcnt(" #n ")" ::: "memory")
#define LGKMCNT0 asm volatile("s_waitcnt lgkmcnt(0)" ::: "memory")
#define SBAR __builtin_amdgcn_s_barrier()

// ---------------- weights f32->bf16 + bias pack ----------------
__global__ __launch_bounds__(256) void wconv_kernel(
    const float* __restrict__ wq, const float* __restrict__ wk,
    const float* __restrict__ wv, const float* __restrict__ wp,
    const float* __restrict__ bq, const float* __restrict__ bk,
    const float* __restrict__ bv, const float* __restrict__ bp,
    bf16* __restrict__ dst, float* __restrict__ bpk)
{
    int i = blockIdx.x * 256 + threadIdx.x;
    dst[i]            = (bf16)wq[i];
    dst[262144 + i]   = (bf16)wk[i];
    dst[2*262144 + i] = (bf16)wv[i];
    dst[3*262144 + i] = (bf16)wp[i];
    if (i < 2048) {
        int j = i >> 9, c = i & 511;
        const float* s = j == 0 ? bq : j == 1 ? bk : j == 2 ? bv : bp;
        bpk[i] = s[c];
    }
}

// ---------------- GroupNorm -> transposed bf16 [b][hw][c] ----------------
__global__ __launch_bounds__(256) void gn_kernel(
    const float* __restrict__ x, const float* __restrict__ scale,
    const float* __restrict__ bias, bf16* __restrict__ outT)
{
    int blk = blockIdx.x;
    int b = blk >> 5, g = blk & 31;
    int c0 = g * kCPG;
    const float* xg = x + ((size_t)b * kC + c0) * kHW;

    float s = 0.f, s2 = 0.f;
    const float4* xg4 = reinterpret_cast<const float4*>(xg);
#pragma unroll
    for (int i = 0; i < 16; ++i) {
        float4 v = xg4[threadIdx.x + i * 256];
        s  += v.x + v.y + v.z + v.w;
        s2 += v.x*v.x + v.y*v.y + v.z*v.z + v.w*v.w;
    }
    s = wave_sum(s); s2 = wave_sum(s2);
    __shared__ float red[8];
    int lane = threadIdx.x & 63, wid = threadIdx.x >> 6;
    if (!lane) { red[wid] = s; red[4 + wid] = s2; }
    __syncthreads();
    float ts = red[0] + red[1] + red[2] + red[3];
    float t2 = red[4] + red[5] + red[6] + red[7];
    float mean = ts * (1.f / 16384.f);
    float var  = t2 * (1.f / 16384.f) - mean * mean;
    float inv  = rsqrtf(var + 1e-6f);

    int ci = threadIdx.x & 15;
    float a  = inv * scale[c0 + ci];
    float bb = bias[c0 + ci] - mean * a;
#pragma unroll
    for (int i = 0; i < 64; ++i) {
        int f = threadIdx.x + i * 256;
        int sp = f >> 4;
        float v = xg[ci * kHW + sp];
        outT[((size_t)b * kHW + sp) * kC + c0 + ci] = (bf16)(v * a + bb);
    }
}

// ============= 8-wave deep-pipelined NT GEMM (BM=256,BN=128,BK=32) ========
// ring-4 LDS slots, global_load_lds w/ pre-swizzled source, counted vmcnt(6),
// raw s_barrier (no drain), setprio around MFMA. K fixed at 512 (NT=16).
// Grid 1D: XCD swizzle -> job (batch/conv) -> by (M/256) -> bx (N/128).
template <int BIAS, bool RESID, typename OUT_T, bool STATS>
__global__ __launch_bounds__(512, 2) void gemm8(
    const bf16* __restrict__ Ab, size_t sA, int lda,
    const bf16* __restrict__ Bb, size_t sB, int ldb,
    OUT_T* __restrict__ Cb, size_t sC, int ldc,
    const float* __restrict__ biasB, int sBias,
    const float* __restrict__ residB, size_t sR,
    float alpha, float* __restrict__ statsOut,
    int nbx, int nby)
{
    __shared__ u16 lds[4 * 8192 + 4 * 4096];   // 96KB: 4 A slots, 4 B slots
    constexpr int NT = 16;                      // K=512, BK=32

    int bid = blockIdx.x, nwg = gridDim.x;
    int swz = (bid & 7) * (nwg >> 3) + (bid >> 3);
    int bpj = nbx * nby;
    int job = swz / bpj, rem = swz % bpj;
    int by = rem / nbx, bx = rem % nbx;
    int brow = by * 256, bcol = bx * 128;

    const u16* Au = reinterpret_cast<const u16*>(Ab + (size_t)job * sA);
    const u16* Bu = reinterpret_cast<const u16*>(Bb + (size_t)job * sB);

    int t = threadIdx.x;
    int lane = t & 63, w = t >> 6;
    int wm = w >> 2, wn = w & 3;
    int cc = lane & 15, nib = lane >> 4;
    int gsw = (nib ^ ((cc >> 1) & 3)) * 8;      // read-side swizzled granule

    int srow = t >> 2;                           // staging row 0..127
    int sglog = ((t & 3) ^ ((t >> 3) & 3)) * 8;  // source granule (pre-swizzle)
    const u16* Asrc0 = Au + (size_t)(brow + srow) * lda + sglog;
    const u16* Asrc1 = Asrc0 + (size_t)128 * lda;
    const u16* Bsrc  = Bu + (size_t)(bcol + srow) * ldb + sglog;
    u16* LA = lds;
    u16* LB = lds + 4 * 8192;
    u16* dA0 = LA + t * 8;
    u16* dA1 = LA + 4096 + t * 8;
    u16* dB  = LB + t * 8;

    f32x4 acc[8][2] = {};

#define STAGE8(kt) { int sl_ = (kt) & 3, k0_ = (kt) * 32;                 \
        gload_lds16(Asrc0 + k0_, dA0 + sl_ * 8192);                       \
        gload_lds16(Asrc1 + k0_, dA1 + sl_ * 8192);                       \
        gload_lds16(Bsrc  + k0_, dB  + sl_ * 4096); }

    STAGE8(0); STAGE8(1); STAGE8(2);
    VMCNT(6);
    SBAR;

    const u16* rA = LA + (wm * 128 + cc) * 32 + gsw;
    const u16* rB = LB + (wn * 32  + cc) * 32 + gsw;

#pragma unroll
    for (int kt = 0; kt < NT; ++kt) {
        int sl = kt & 3;
        bf16x8 a[8], b[2];
#pragma unroll
        for (int n = 0; n < 2; ++n)
            b[n] = *reinterpret_cast<const bf16x8*>(rB + sl * 4096 + n * 512);
#pragma unroll
        for (int m = 0; m < 8; ++m)
            a[m] = *reinterpret_cast<const bf16x8*>(rA + sl * 8192 + m * 512);
        if (kt + 3 < NT) STAGE8(kt + 3);
        SBAR;
        __builtin_amdgcn_s_setprio(1);
#pragma unroll
        for (int m = 0; m < 8; ++m)
#pragma unroll
            for (int n = 0; n < 2; ++n)
                acc[m][n] = __builtin_amdgcn_mfma_f32_16x16x32_bf16(a[m], b[n], acc[m][n], 0, 0, 0);
        __builtin_amdgcn_s_setprio(0);
        if (kt + 3 < NT)      { VMCNT(6); }
        else if (kt + 2 < NT) { VMCNT(3); }
        else if (kt + 1 < NT) { VMCNT(0); }
        SBAR;
    }

#pragma unroll
    for (int m = 0; m < 8; ++m)
#pragma unroll
        for (int n = 0; n < 2; ++n)
#pragma unroll
            for (int r = 0; r < 4; ++r)
                acc[m][n][r] *= alpha;

    if constexpr (STATS) {
        __shared__ float sred[2][4][256];
        float rmax[8][4];
#pragma unroll
        for (int m = 0; m < 8; ++m)
#pragma unroll
            for (int r = 0; r < 4; ++r) {
                float v_ = fmaxf(acc[m][0][r], acc[m][1][r]);
                v_ = fmaxf(v_, __shfl_xor(v_, 1, 64));
                v_ = fmaxf(v_, __shfl_xor(v_, 2, 64));
                v_ = fmaxf(v_, __shfl_xor(v_, 4, 64));
                v_ = fmaxf(v_, __shfl_xor(v_, 8, 64));
                rmax[m][r] = v_;
            }
        if (cc == 0)
#pragma unroll
            for (int m = 0; m < 8; ++m)
#pragma unroll
                for (int r = 0; r < 4; ++r)
                    sred[0][wn][wm * 128 + m * 16 + nib * 4 + r] = rmax[m][r];
        __syncthreads();
#pragma unroll
        for (int m = 0; m < 8; ++m)
#pragma unroll
            for (int r = 0; r < 4; ++r) {
                int lr = wm * 128 + m * 16 + nib * 4 + r;
                rmax[m][r] = fmaxf(fmaxf(sred[0][0][lr], sred[0][1][lr]),
                                   fmaxf(sred[0][2][lr], sred[0][3][lr]));
            }
#pragma unroll
        for (int m = 0; m < 8; ++m)
#pragma unroll
            for (int r = 0; r < 4; ++r) {
                float s_ = __expf(acc[m][0][r] - rmax[m][r]) +
                           __expf(acc[m][1][r] - rmax[m][r]);
                s_ += __shfl_xor(s_, 1, 64);
                s_ += __shfl_xor(s_, 2, 64);
                s_ += __shfl_xor(s_, 4, 64);
                s_ += __shfl_xor(s_, 8, 64);
                if (cc == 0)
                    sred[1][wn][wm * 128 + m * 16 + nib * 4 + r] = s_;
            }
        __syncthreads();
        if (t < 256) {
            float M = fmaxf(fmaxf(sred[0][0][t], sred[0][1][t]),
                            fmaxf(sred[0][2][t], sred[0][3][t]));
            float L = sred[1][0][t] + sred[1][1][t] + sred[1][2][t] + sred[1][3][t];
            size_t off = ((size_t)(job * 1024 + brow + t)) * 16 + bx * 2;
            statsOut[off]     = M;
            statsOut[off + 1] = L;
        }
    }

    OUT_T* Cj = Cb + (size_t)job * sC;
    const float* bias = biasB + (size_t)job * sBias;
#pragma unroll
    for (int m = 0; m < 8; ++m) {
#pragma unroll
        for (int n = 0; n < 2; ++n) {
#pragma unroll
            for (int r = 0; r < 4; ++r) {
                int grow = brow + wm * 128 + m * 16 + nib * 4 + r;
                int gcol = bcol + wn * 32 + n * 16 + cc;
                float vv = acc[m][n][r];
                if (BIAS == 1) vv += bias[grow];
                if (BIAS == 2) vv += bias[gcol];
                if (RESID)     vv += residB[(size_t)job * sR + (size_t)grow * ldc + gcol];
                Cj[(size_t)grow * ldc + gcol] = (OUT_T)vv;
            }
        }
    }
#undef STAGE8
}

// ============= fused softmax + PV, same pipeline ===========================
// A = exp(S - M) built in-register (f32 load -> exp -> bf16 -> swizzled
// ds_write, 2 tiles ahead); B = V via global_load_lds; epilogue /L.
__global__ __launch_bounds__(512, 2) void pv8(
    const float* __restrict__ S, const float* __restrict__ stats,
    const bf16* __restrict__ V, bf16* __restrict__ O)
{
    __shared__ u16 lds[4 * 8192 + 4 * 4096];
    __shared__ float Ml[256], Ll[256];
    constexpr int NT = 32;                      // K=1024, BK=32

    int bid = blockIdx.x, nwg = gridDim.x;
    int swz = (bid & 7) * (nwg >> 3) + (bid >> 3);
    int job = swz >> 4, rem = swz & 15;
    int by = rem >> 2, bx = rem & 3;
    int brow = by * 256, bcol = bx * 128;

    int t = threadIdx.x;
    int lane = t & 63, w = t >> 6;
    int wm = w >> 2, wn = w & 3;
    int cc = lane & 15, nib = lane >> 4;
    int gsw = (nib ^ ((cc >> 1) & 3)) * 8;

    if (t < 256) {
        const float* st = stats + ((size_t)(job * 1024 + brow + t)) * 16;
        float M = st[0];
#pragma unroll
        for (int k = 1; k < 8; ++k) M = fmaxf(M, st[2 * k]);
        float L = 0.f;
#pragma unroll
        for (int k = 0; k < 8; ++k) L += st[2 * k + 1] * __expf(st[2 * k] - M);
        Ml[t] = M; Ll[t] = L;
    }
    __syncthreads();

    int srow = t >> 2;
    float am0 = Ml[srow], am1 = Ml[128 + srow];
    int sglog = ((t & 3) ^ ((t >> 3) & 3)) * 8;
    const float* Ss0 = S + (size_t)job * 1048576 + (size_t)(brow + srow) * 1024 + sglog;
    const float* Ss1 = Ss0 + 128 * 1024;
    const u16* Vu = reinterpret_cast<const u16*>(V) + (size_t)job * 524288
                    + (size_t)(bcol + srow) * 1024 + sglog;
    u16* LA = lds;
    u16* LB = lds + 4 * 8192;
    u16* dB = LB + t * 8;
    const u16* rA = LA + (wm * 128 + cc) * 32 + gsw;
    const u16* rB = LB + (wn * 32  + cc) * 32 + gsw;

    f32x4 acc[8][2] = {};
    float4 pa0, pa1, pa2, pa3, qa0, qa1, qa2, qa3;

#define STAGEB(T) gload_lds16(Vu + (T) * 32, dB + ((T) & 3) * 4096)
#define LOADS(T, R0, R1, R2, R3) { int k0_ = (T) * 32;                    \
        R0 = *reinterpret_cast<const float4*>(Ss0 + k0_);                 \
        R1 = *reinterpret_cast<const float4*>(Ss0 + k0_ + 4);             \
        R2 = *reinterpret_cast<const float4*>(Ss1 + k0_);                 \
        R3 = *reinterpret_cast<const float4*>(Ss1 + k0_ + 4); }
#define WRITEA(T, R0, R1, R2, R3) { int sl_ = (T) & 3;                    \
        bf16x8 p0_, p1_;                                                  \
        p0_[0] = (bf16)__expf(R0.x - am0); p0_[1] = (bf16)__expf(R0.y - am0); \
        p0_[2] = (bf16)__expf(R0.z - am0); p0_[3] = (bf16)__expf(R0.w - am0); \
        p0_[4] = (bf16)__expf(R1.x - am0); p0_[5] = (bf16)__expf(R1.y - am0); \
        p0_[6] = (bf16)__expf(R1.z - am0); p0_[7] = (bf16)__expf(R1.w - am0); \
        p1_[0] = (bf16)__expf(R2.x - am1); p1_[1] = (bf16)__expf(R2.y - am1); \
        p1_[2] = (bf16)__expf(R2.z - am1); p1_[3] = (bf16)__expf(R2.w - am1); \
        p1_[4] = (bf16)__expf(R3.x - am1); p1_[5] = (bf16)__expf(R3.y - am1); \
        p1_[6] = (bf16)__expf(R3.z - am1); p1_[7] = (bf16)__expf(R3.w - am1); \
        *reinterpret_cast<bf16x8*>(LA + sl_ * 8192 + t * 8) = p0_;        \
        *reinterpret_cast<bf16x8*>(LA + sl_ * 8192 + 4096 + t * 8) = p1_; }

    // prologue: A0 written, S1/S2 in regs, B0..2 staged
    LOADS(0, pa0, pa1, pa2, pa3);
    WRITEA(0, pa0, pa1, pa2, pa3);
    LOADS(1, pa0, pa1, pa2, pa3);
    LOADS(2, qa0, qa1, qa2, qa3);
    STAGEB(0); STAGEB(1); STAGEB(2);
    VMCNT(2);
    LGKMCNT0;
    SBAR;

#define PVPHASE(T, R0, R1, R2, R3)                                        \
    {                                                                     \
        int sl_p = (T) & 3;                                               \
        bf16x8 a_[8], b_[2];                                              \
        _Pragma("unroll")                                                 \
        for (int n = 0; n < 2; ++n)                                       \
            b_[n] = *reinterpret_cast<const bf16x8*>(rB + sl_p * 4096 + n * 512); \
        _Pragma("unroll")                                                 \
        for (int m = 0; m < 8; ++m)                                       \
            a_[m] = *reinterpret_cast<const bf16x8*>(rA + sl_p * 8192 + m * 512); \
        if ((T) + 3 < NT) STAGEB((T) + 3);                                \
        SBAR;                                                             \
        __builtin_amdgcn_s_setprio(1);                                    \
        _Pragma("unroll")                                                 \
        for (int m = 0; m < 8; ++m)                                       \
            _Pragma("unroll")                                             \
            for (int n = 0; n < 2; ++n)                                   \
                acc[m][n] = __builtin_amdgcn_mfma_f32_16x16x32_bf16(a_[m], b_[n], acc[m][n], 0, 0, 0); \
        __builtin_amdgcn_s_setprio(0);                                    \
        if ((T) + 1 < NT) WRITEA((T) + 1, R0, R1, R2, R3);                \
        if ((T) + 3 < NT) LOADS((T) + 3, R0, R1, R2, R3);                 \
        LGKMCNT0;                                                         \
        if ((T) == 0)          { VMCNT(5); }                              \
        else if ((T) + 3 < NT) { VMCNT(9); }                              \
        else                   { VMCNT(0); }                              \
        SBAR;                                                             \
    }

    for (int kt = 0; kt < NT; kt += 2) {
        PVPHASE(kt,     pa0, pa1, pa2, pa3);
        PVPHASE(kt + 1, qa0, qa1, qa2, qa3);
    }

    bf16* Oj = O + (size_t)job * 524288;
#pragma unroll
    for (int m = 0; m < 8; ++m) {
#pragma unroll
        for (int r = 0; r < 4; ++r) {
            int lr = wm * 128 + m * 16 + nib * 4 + r;
            float linv = 1.0f / Ll[lr];
#pragma unroll
            for (int n = 0; n < 2; ++n) {
                int gcol = bcol + wn * 32 + n * 16 + cc;
                Oj[(size_t)(brow + lr) * 512 + gcol] = (bf16)(acc[m][n][r] * linv);
            }
        }
    }
#undef STAGEB
#undef LOADS
#undef WRITEA
#undef PVPHASE
}

extern "C" void kernel_launch(void* const* d_in, const int* in_sizes, int n_in,
                              void* d_out, int out_size, void* d_ws, size_t ws_size,
                              hipStream_t stream)
{
    const float* x   = (const float*)d_in[0];
    const float* y   = (const float*)d_in[1];
    const float* ns  = (const float*)d_in[2];
    const float* nb  = (const float*)d_in[3];
    const float* n1s = (const float*)d_in[4];
    const float* n1b = (const float*)d_in[5];
    const float* wq  = (const float*)d_in[6];
    const float* bq  = (const float*)d_in[7];
    const float* wk  = (const float*)d_in[8];
    const float* bk  = (const float*)d_in[9];
    const float* wv  = (const float*)d_in[10];
    const float* bv  = (const float*)d_in[11];
    const float* wp  = (const float*)d_in[12];
    const float* bp  = (const float*)d_in[13];
    float* out = (float*)d_out;

    char* ws = (char*)d_ws;
    bf16* wbf  = (bf16*)ws;                          // 2 MB: wq,wk,wv,wp bf16
    float* bpk = (float*)(ws + 2097152);             // 8 KB packed biases
    bf16* ynT = (bf16*)(ws + 2105344);               // [b][hw][c] (q input)
    bf16* hnT = ynT + 8388608;                       // [b][hw][c] (k/v input)
    bf16* qT  = hnT + 8388608;
    bf16* kT  = qT  + 8388608;
    bf16* v   = kT  + 8388608;                       // [b][c][hw]
    float* stats = (float*)ynT;                      // ynT dead after q conv
    bf16* aoT = qT;                                  // qT dead after QK^T
    float* S  = (float*)(ws + 2105344 + 5ull * 16777216);   // 64 MB f32

    const size_t sBC = (size_t)kHW * kC;
    const float scl = 0.044194173824159216f;         // 512^-0.5

    wconv_kernel<<<1024, 256, 0, stream>>>(wq, wk, wv, wp, bq, bk, bv, bp, wbf, bpk);
    gn_kernel<<<512, 256, 0, stream>>>(y, n1s, n1b, ynT);
    gn_kernel<<<512, 256, 0, stream>>>(x, ns,  nb,  hnT);

    // q & k convs fused: job0 = ynT·wq -> qT, job1 = hnT·wk -> kT  (M=16384)
    gemm8<2, false, bf16, false><<<512, 512, 0, stream>>>(
        ynT, 8388608, 512, wbf, 262144, 512, qT, 8388608, 512,
        bpk, 512, nullptr, 0, 1.f, nullptr, 4, 64);
    // v conv per batch: wv[o][c] · hnT[n][c] -> v[o][n]
    gemm8<1, false, bf16, false><<<256, 512, 0, stream>>>(
        wbf + 2 * 262144, 0, 512, hnT, sBC, 512, v, sBC, 1024,
        bpk + 1024, 0, nullptr, 0, 1.f, nullptr, 8, 2);
    // QK^T + stats: S = scl * qT·kT^T
    gemm8<0, false, float, true><<<512, 512, 0, stream>>>(
        qT, sBC, 512, kT, sBC, 512, S, 1048576, 1024,
        bpk, 0, nullptr, 0, scl, stats, 8, 4);
    // fused softmax + PV -> aoT [b][hw][c]
    pv8<<<256, 512, 0, stream>>>(S, stats, v, aoT);
    // proj + bias + residual: out[o][n] = wp·aoT + bp + x
    gemm8<1, true, float, false><<<256, 512, 0, stream>>>(
        wbf + 3 * 262144, 0, 512, aoT, sBC, 512, out, sBC, 1024,
        bpk + 1536, 0, x, sBC, 1.f, nullptr, 8, 2);
}

// Round 5
// 192.441 us; speedup vs baseline: 1.1398x; 1.0308x over previous
//
#include <hip/hip_runtime.h>
#include <hip/hip_bf16.h>

typedef __bf16 bf16;
typedef __bf16 bf16x8 __attribute__((ext_vector_type(8)));
typedef float f32x4 __attribute__((ext_vector_type(4)));
typedef unsigned short u16;
typedef unsigned short u16x8 __attribute__((ext_vector_type(8)));

constexpr int kHW = 1024;
constexpr int kC  = 512;
constexpr int kCPG = 16;

__device__ inline float wave_sum(float v) {
#pragma unroll
    for (int o = 32; o; o >>= 1) v += __shfl_xor(v, o, 64);
    return v;
}

__device__ inline void gload_lds16(const void* g, void* l) {
    __builtin_amdgcn_global_load_lds(
        (const __attribute__((address_space(1))) void*)g,
        (__attribute__((address_space(3))) void*)l, 16, 0, 0);
}

#define VMCNT(n) asm volatile("s_waitcnt vmcnt(" #n ")" ::: "memory")
#define SBAR __builtin_amdgcn_s_barrier()
#define NOP do {} while (0)

// ---------------- weights f32->bf16 + bias pack ----------------
__global__ __launch_bounds__(256) void wconv_kernel(
    const float* __restrict__ wq, const float* __restrict__ wk,
    const float* __restrict__ wv, const float* __restrict__ wp,
    const float* __restrict__ bq, const float* __restrict__ bk,
    const float* __restrict__ bv, const float* __restrict__ bp,
    bf16* __restrict__ dst, float* __restrict__ bpk)
{
    int i = blockIdx.x * 256 + threadIdx.x;
    dst[i]            = (bf16)wq[i];
    dst[262144 + i]   = (bf16)wk[i];
    dst[2*262144 + i] = (bf16)wv[i];
    dst[3*262144 + i] = (bf16)wp[i];
    if (i < 2048) {
        int j = i >> 9, c = i & 511;
        const float* s = j == 0 ? bq : j == 1 ? bk : j == 2 ? bv : bp;
        bpk[i] = s[c];
    }
}

// ---------------- GroupNorm -> transposed bf16 [b][hw][c] ----------------
__global__ __launch_bounds__(256) void gn_kernel(
    const float* __restrict__ x, const float* __restrict__ scale,
    const float* __restrict__ bias, bf16* __restrict__ outT)
{
    int blk = blockIdx.x;
    int b = blk >> 5, g = blk & 31;
    int c0 = g * kCPG;
    const float* xg = x + ((size_t)b * kC + c0) * kHW;

    float s = 0.f, s2 = 0.f;
    const float4* xg4 = reinterpret_cast<const float4*>(xg);
#pragma unroll
    for (int i = 0; i < 16; ++i) {
        float4 v = xg4[threadIdx.x + i * 256];
        s  += v.x + v.y + v.z + v.w;
        s2 += v.x*v.x + v.y*v.y + v.z*v.z + v.w*v.w;
    }
    s = wave_sum(s); s2 = wave_sum(s2);
    __shared__ float red[8];
    int lane = threadIdx.x & 63, wid = threadIdx.x >> 6;
    if (!lane) { red[wid] = s; red[4 + wid] = s2; }
    __syncthreads();
    float ts = red[0] + red[1] + red[2] + red[3];
    float t2 = red[4] + red[5] + red[6] + red[7];
    float mean = ts * (1.f / 16384.f);
    float var  = t2 * (1.f / 16384.f) - mean * mean;
    float inv  = rsqrtf(var + 1e-6f);

    int ci = threadIdx.x & 15;
    float a  = inv * scale[c0 + ci];
    float bb = bias[c0 + ci] - mean * a;
#pragma unroll
    for (int i = 0; i < 64; ++i) {
        int f = threadIdx.x + i * 256;
        int sp = f >> 4;
        float v = xg[ci * kHW + sp];
        outT[((size_t)b * kHW + sp) * kC + c0 + ci] = (bf16)(v * a + bb);
    }
}

// ======== 256x256 8-phase NT GEMM (m201 geometry), K=512 fixed ===========
// 8 waves 2Mx4N, per-wave 128x64 (m8n4). BK=64. Quarter-tile (64row x 64col
// = 8KB = one gload_lds across 512 threads) staging, 2-buf x 4-quarter ring.
// XOR-granule swizzle both sides. vmcnt(4) before even-phase close barriers.
template <int BIAS, bool RESID, typename OUT_T, bool STATS, int NBX, int NBY>
__global__ __launch_bounds__(512, 2) void gemm256(
    const bf16* __restrict__ Ab, size_t sA, int lda,
    const bf16* __restrict__ Bb, size_t sB, int ldb,
    OUT_T* __restrict__ Cb, size_t sC, int ldc,
    const float* __restrict__ biasB, int sBias,
    const float* __restrict__ residB, size_t sR,
    float alpha, float* __restrict__ statsOut)
{
    __shared__ u16 lds[65536];           // 128KB: A 8x8KB slots, B 8x8KB
    constexpr int NT = 8;                // K = 512
    constexpr int NITER = NT / 2;

    int bid = blockIdx.x, nwg = gridDim.x;
    int swz = (bid & 7) * (nwg >> 3) + (bid >> 3);
    int job = swz / (NBX * NBY), rem = swz % (NBX * NBY);
    int by = rem / NBX, bx = rem % NBX;
    int brow = by * 256, bcol = bx * 256;

    const u16* Au = reinterpret_cast<const u16*>(Ab + (size_t)job * sA);
    const u16* Bu = reinterpret_cast<const u16*>(Bb + (size_t)job * sB);

    int t = threadIdx.x;
    int lane = t & 63, w = t >> 6;
    int wm = w >> 2, wn = w & 3;
    int cc = lane & 15, nib = lane >> 4;

    int trow = t >> 3;                               // 0..63
    int gsrc = ((t & 7) ^ (trow & 7)) * 8;           // pre-swizzled src granule
    const u16* Asrc = Au + (size_t)(brow + trow) * lda + gsrc;
    const u16* Bsrc = Bu + (size_t)(bcol + trow) * ldb + gsrc;
    u16* LDSA = lds;
    u16* LDSB = lds + 32768;

#define STAGE_A(TL, Q) gload_lds16(Asrc + (size_t)(Q) * 64 * lda + (TL) * 64, \
                                   LDSA + (((TL)&1)*4 + (Q)) * 4096 + t * 8)
#define STAGE_B(TL, Q) gload_lds16(Bsrc + (size_t)(Q) * 64 * ldb + (TL) * 64, \
                                   LDSB + (((TL)&1)*4 + (Q)) * 4096 + t * 8)

    f32x4 acc[8][4] = {};
    bf16x8 afr[4][2], bfr[4][2];

#define PHASE(MH, NH, TL, STG1, STG2, VMW)                                    \
  {                                                                           \
    if ((NH) == 0) {                                                          \
      _Pragma("unroll") for (int mi = 0; mi < 4; ++mi)                        \
      _Pragma("unroll") for (int kx = 0; kx < 2; ++kx)                        \
        afr[mi][kx] = *reinterpret_cast<const bf16x8*>(LDSA +                 \
            (((TL)&1)*4 + wm*2 + (MH)) * 4096 + (mi*16 + cc) * 64 +           \
            (((nib + kx*4) ^ (cc & 7)) * 8));                                 \
    }                                                                         \
    if ((MH) == 0) {                                                          \
      _Pragma("unroll") for (int ni = 0; ni < 2; ++ni)                        \
      _Pragma("unroll") for (int kx = 0; kx < 2; ++kx)                        \
        bfr[(NH)*2 + ni][kx] = *reinterpret_cast<const bf16x8*>(LDSB +        \
            (((TL)&1)*4 + wn) * 4096 + (((NH)*2 + ni)*16 + cc) * 64 +         \
            (((nib + kx*4) ^ (cc & 7)) * 8));                                 \
    }                                                                         \
    STG1; STG2;                                                               \
    SBAR;                                                                     \
    __builtin_amdgcn_s_setprio(1);                                            \
    _Pragma("unroll") for (int mi = 0; mi < 4; ++mi)                          \
    _Pragma("unroll") for (int ni = 0; ni < 2; ++ni)                          \
    _Pragma("unroll") for (int kx = 0; kx < 2; ++kx)                          \
      acc[(MH)*4 + mi][(NH)*2 + ni] = __builtin_amdgcn_mfma_f32_16x16x32_bf16(\
          afr[mi][kx], bfr[(NH)*2 + ni][kx], acc[(MH)*4 + mi][(NH)*2 + ni],   \
          0, 0, 0);                                                           \
    __builtin_amdgcn_s_setprio(0);                                            \
    VMW;                                                                      \
    SBAR;                                                                     \
  }

    // prologue: Aq02(T0), Bq01(T0), Bq23(T0), Aq02(T1), Aq13(T0) = 10 loads
    STAGE_A(0, 0); STAGE_A(0, 2);
    STAGE_B(0, 0); STAGE_B(0, 1);
    STAGE_B(0, 2); STAGE_B(0, 3);
    STAGE_A(1, 0); STAGE_A(1, 2);
    STAGE_A(0, 1); STAGE_A(0, 3);
    VMCNT(4);
    SBAR;

    for (int j = 0; j < NITER - 1; ++j) {
        int T0 = 2 * j, T1 = 2 * j + 1, T2 = 2 * j + 2, T3 = 2 * j + 3;
        PHASE(0, 0, T0, STAGE_B(T1, 0), STAGE_B(T1, 1), NOP);
        PHASE(0, 1, T0, STAGE_B(T1, 2), STAGE_B(T1, 3), VMCNT(4));
        PHASE(1, 0, T0, STAGE_A(T2, 0), STAGE_A(T2, 2), NOP);
        PHASE(1, 1, T0, STAGE_A(T1, 1), STAGE_A(T1, 3), VMCNT(4));
        PHASE(0, 0, T1, STAGE_B(T2, 0), STAGE_B(T2, 1), NOP);
        PHASE(0, 1, T1, STAGE_B(T2, 2), STAGE_B(T2, 3), VMCNT(4));
        PHASE(1, 0, T1, STAGE_A(T3, 0), STAGE_A(T3, 2), NOP);
        PHASE(1, 1, T1, STAGE_A(T2, 1), STAGE_A(T2, 3), VMCNT(4));
    }
    {   // last iteration: tiles NT-2, NT-1; drain 4 -> 2 -> 0
        int T0 = NT - 2, T1 = NT - 1;
        PHASE(0, 0, T0, STAGE_B(T1, 0), STAGE_B(T1, 1), NOP);
        PHASE(0, 1, T0, STAGE_B(T1, 2), STAGE_B(T1, 3), VMCNT(4));
        PHASE(1, 0, T0, NOP, NOP, NOP);
        PHASE(1, 1, T0, STAGE_A(T1, 1), STAGE_A(T1, 3), VMCNT(2));
        PHASE(0, 0, T1, NOP, NOP, NOP);
        PHASE(0, 1, T1, NOP, NOP, VMCNT(0));
        PHASE(1, 0, T1, NOP, NOP, NOP);
        PHASE(1, 1, T1, NOP, NOP, NOP);
    }
#undef PHASE
#undef STAGE_A
#undef STAGE_B

#pragma unroll
    for (int m = 0; m < 8; ++m)
#pragma unroll
        for (int n = 0; n < 4; ++n)
#pragma unroll
            for (int r = 0; r < 4; ++r)
                acc[m][n][r] *= alpha;

    if constexpr (STATS) {
        // tiles dead; reuse LDS for cross-wave row reduction
        float* sredM = reinterpret_cast<float*>(lds);          // [4][256]
        float* sredS = reinterpret_cast<float*>(lds) + 1024;   // [4][256]
        float rmax[8][4];
#pragma unroll
        for (int m = 0; m < 8; ++m)
#pragma unroll
            for (int r = 0; r < 4; ++r) {
                float v_ = fmaxf(fmaxf(acc[m][0][r], acc[m][1][r]),
                                 fmaxf(acc[m][2][r], acc[m][3][r]));
                v_ = fmaxf(v_, __shfl_xor(v_, 1, 64));
                v_ = fmaxf(v_, __shfl_xor(v_, 2, 64));
                v_ = fmaxf(v_, __shfl_xor(v_, 4, 64));
                v_ = fmaxf(v_, __shfl_xor(v_, 8, 64));
                rmax[m][r] = v_;
            }
        if (cc == 0)
#pragma unroll
            for (int m = 0; m < 8; ++m)
#pragma unroll
                for (int r = 0; r < 4; ++r)
                    sredM[wn * 256 + wm * 128 + m * 16 + nib * 4 + r] = rmax[m][r];
        __syncthreads();
#pragma unroll
        for (int m = 0; m < 8; ++m)
#pragma unroll
            for (int r = 0; r < 4; ++r) {
                int lr = wm * 128 + m * 16 + nib * 4 + r;
                rmax[m][r] = fmaxf(fmaxf(sredM[lr], sredM[256 + lr]),
                                   fmaxf(sredM[512 + lr], sredM[768 + lr]));
            }
#pragma unroll
        for (int m = 0; m < 8; ++m)
#pragma unroll
            for (int r = 0; r < 4; ++r) {
                float s_ = __expf(acc[m][0][r] - rmax[m][r]) +
                           __expf(acc[m][1][r] - rmax[m][r]) +
                           __expf(acc[m][2][r] - rmax[m][r]) +
                           __expf(acc[m][3][r] - rmax[m][r]);
                s_ += __shfl_xor(s_, 1, 64);
                s_ += __shfl_xor(s_, 2, 64);
                s_ += __shfl_xor(s_, 4, 64);
                s_ += __shfl_xor(s_, 8, 64);
                if (cc == 0)
                    sredS[wn * 256 + wm * 128 + m * 16 + nib * 4 + r] = s_;
            }
        __syncthreads();
        if (t < 256) {
            float M = fmaxf(fmaxf(sredM[t], sredM[256 + t]),
                            fmaxf(sredM[512 + t], sredM[768 + t]));
            float L = sredS[t] + sredS[256 + t] + sredS[512 + t] + sredS[768 + t];
            size_t off = ((size_t)(job * 1024 + brow + t)) * 8 + bx * 2;
            statsOut[off]     = M;
            statsOut[off + 1] = L;
        }
    }

    OUT_T* Cj = Cb + (size_t)job * sC;
    const float* bias = biasB + (size_t)job * sBias;
#pragma unroll
    for (int m = 0; m < 8; ++m) {
#pragma unroll
        for (int n = 0; n < 4; ++n) {
#pragma unroll
            for (int r = 0; r < 4; ++r) {
                int grow = brow + wm * 128 + m * 16 + nib * 4 + r;
                int gcol = bcol + wn * 64 + n * 16 + cc;
                float vv = acc[m][n][r];
                if (BIAS == 1) vv += bias[grow];
                if (BIAS == 2) vv += bias[gcol];
                if (RESID)     vv += residB[(size_t)job * sR + (size_t)grow * ldc + gcol];
                Cj[(size_t)grow * ldc + gcol] = (OUT_T)vv;
            }
        }
    }
}

// ======== fused softmax + PV: BM=128, BN=256, BK=32, reg-staged ===========
// A = exp(S - M) built in-reg during staging; B = V via reg stage. Single
// LDS buffer + 2 syncthreads/tile; loads for t+1 issued before compute(t).
__global__ __launch_bounds__(512, 2) void pv_gemm(
    const float* __restrict__ S, const float* __restrict__ stats,
    const bf16* __restrict__ V, bf16* __restrict__ O)
{
    __shared__ u16 ldsA[128 * 32];   // 8KB
    __shared__ u16 ldsB[256 * 32];   // 16KB
    __shared__ float Ml[128], Ll[128];

    int bid = blockIdx.x;
    int swz = (bid & 7) * 32 + (bid >> 3);     // nwg = 256
    int job = swz >> 4, rem = swz & 15;
    int by = rem >> 1, bx = rem & 1;           // NBY=8, NBX=2
    int brow = by * 128, bcol = bx * 256;

    int t = threadIdx.x;
    int lane = t & 63, w = t >> 6;
    int wm = w >> 2, wn = w & 3;
    int cc = lane & 15, nib = lane >> 4;

    if (t < 128) {
        const float* st = stats + ((size_t)(job * 1024 + brow + t)) * 8;
        float M = st[0];
#pragma unroll
        for (int k = 1; k < 4; ++k) M = fmaxf(M, st[2 * k]);
        float L = 0.f;
#pragma unroll
        for (int k = 0; k < 4; ++k) L += st[2 * k + 1] * __expf(st[2 * k] - M);
        Ml[t] = M; Ll[t] = L;
    }
    __syncthreads();

    int ar = t >> 2, ac = (t & 3) * 8;         // A: 128 rows x 32 cols f32
    float am = Ml[ar];
    const float* Sr = S + (size_t)job * 1048576 + (size_t)(brow + ar) * 1024 + ac;
    int br = t >> 1, bc2 = (t & 1) * 16;       // B: 256 rows x 32 cols u16
    const u16* Vr = reinterpret_cast<const u16*>(V) + (size_t)job * 524288
                    + (size_t)(bcol + br) * 1024 + bc2;
    u16* wA = ldsA + ar * 32 + ac;
    u16* wB = ldsB + br * 32 + bc2;

    f32x4 acc[4][4] = {};

    float4 s0 = *reinterpret_cast<const float4*>(Sr);
    float4 s1 = *reinterpret_cast<const float4*>(Sr + 4);
    u16x8 v0 = *reinterpret_cast<const u16x8*>(Vr);
    u16x8 v1 = *reinterpret_cast<const u16x8*>(Vr + 8);
    {
        bf16x8 pw;
        pw[0] = (bf16)__expf(s0.x - am); pw[1] = (bf16)__expf(s0.y - am);
        pw[2] = (bf16)__expf(s0.z - am); pw[3] = (bf16)__expf(s0.w - am);
        pw[4] = (bf16)__expf(s1.x - am); pw[5] = (bf16)__expf(s1.y - am);
        pw[6] = (bf16)__expf(s1.z - am); pw[7] = (bf16)__expf(s1.w - am);
        *reinterpret_cast<bf16x8*>(wA) = pw;
        *reinterpret_cast<u16x8*>(wB) = v0;
        *reinterpret_cast<u16x8*>(wB + 8) = v1;
    }
    __syncthreads();

    for (int kt = 0; kt < 32; ++kt) {
        if (kt < 31) {
            s0 = *reinterpret_cast<const float4*>(Sr + (kt + 1) * 32);
            s1 = *reinterpret_cast<const float4*>(Sr + (kt + 1) * 32 + 4);
            v0 = *reinterpret_cast<const u16x8*>(Vr + (kt + 1) * 32);
            v1 = *reinterpret_cast<const u16x8*>(Vr + (kt + 1) * 32 + 8);
        }
        bf16x8 a[4], b[4];
#pragma unroll
        for (int mi = 0; mi < 4; ++mi)
            a[mi] = *reinterpret_cast<const bf16x8*>(
                ldsA + (wm * 64 + mi * 16 + cc) * 32 + nib * 8);
#pragma unroll
        for (int ni = 0; ni < 4; ++ni)
            b[ni] = *reinterpret_cast<const bf16x8*>(
                ldsB + (wn * 64 + ni * 16 + cc) * 32 + nib * 8);
        __builtin_amdgcn_s_setprio(1);
#pragma unroll
        for (int mi = 0; mi < 4; ++mi)
#pragma unroll
            for (int ni = 0; ni < 4; ++ni)
                acc[mi][ni] = __builtin_amdgcn_mfma_f32_16x16x32_bf16(
                    a[mi], b[ni], acc[mi][ni], 0, 0, 0);
        __builtin_amdgcn_s_setprio(0);
        __syncthreads();
        if (kt < 31) {
            bf16x8 pw;
            pw[0] = (bf16)__expf(s0.x - am); pw[1] = (bf16)__expf(s0.y - am);
            pw[2] = (bf16)__expf(s0.z - am); pw[3] = (bf16)__expf(s0.w - am);
            pw[4] = (bf16)__expf(s1.x - am); pw[5] = (bf16)__expf(s1.y - am);
            pw[6] = (bf16)__expf(s1.z - am); pw[7] = (bf16)__expf(s1.w - am);
            *reinterpret_cast<bf16x8*>(wA) = pw;
            *reinterpret_cast<u16x8*>(wB) = v0;
            *reinterpret_cast<u16x8*>(wB + 8) = v1;
        }
        __syncthreads();
    }

#pragma unroll
    for (int mi = 0; mi < 4; ++mi) {
#pragma unroll
        for (int r = 0; r < 4; ++r) {
            int lr = wm * 64 + mi * 16 + nib * 4 + r;
            float linv = 1.0f / Ll[lr];
#pragma unroll
            for (int ni = 0; ni < 4; ++ni) {
                int gcol = bcol + wn * 64 + ni * 16 + cc;
                O[(size_t)job * 524288 + (size_t)(brow + lr) * 512 + gcol] =
                    (bf16)(acc[mi][ni][r] * linv);
            }
        }
    }
}

extern "C" void kernel_launch(void* const* d_in, const int* in_sizes, int n_in,
                              void* d_out, int out_size, void* d_ws, size_t ws_size,
                              hipStream_t stream)
{
    const float* x   = (const float*)d_in[0];
    const float* y   = (const float*)d_in[1];
    const float* ns  = (const float*)d_in[2];
    const float* nb  = (const float*)d_in[3];
    const float* n1s = (const float*)d_in[4];
    const float* n1b = (const float*)d_in[5];
    const float* wq  = (const float*)d_in[6];
    const float* bq  = (const float*)d_in[7];
    const float* wk  = (const float*)d_in[8];
    const float* bk  = (const float*)d_in[9];
    const float* wv  = (const float*)d_in[10];
    const float* bv  = (const float*)d_in[11];
    const float* wp  = (const float*)d_in[12];
    const float* bp  = (const float*)d_in[13];
    float* out = (float*)d_out;

    char* ws = (char*)d_ws;
    bf16* wbf  = (bf16*)ws;                          // 2 MB weights bf16
    float* bpk = (float*)(ws + 2097152);             // 8 KB biases
    bf16* ynT = (bf16*)(ws + 2105344);               // [b][hw][c]
    bf16* hnT = ynT + 8388608;
    bf16* qT  = hnT + 8388608;
    bf16* kT  = qT  + 8388608;
    bf16* v   = kT  + 8388608;                       // [b][c][hw]
    float* stats = (float*)ynT;                      // ynT dead after q/k conv
    bf16* aoT = qT;                                  // qT dead after QK^T
    float* S  = (float*)(ws + 2105344 + 5ull * 16777216);   // 64 MB f32

    const size_t sBC = (size_t)kHW * kC;
    const float scl = 0.044194173824159216f;         // 512^-0.5

    wconv_kernel<<<1024, 256, 0, stream>>>(wq, wk, wv, wp, bq, bk, bv, bp, wbf, bpk);
    gn_kernel<<<512, 256, 0, stream>>>(y, n1s, n1b, ynT);
    gn_kernel<<<512, 256, 0, stream>>>(x, ns,  nb,  hnT);

    // q & k convs fused (jobs 0/1): out_T[i][o] = in_T[i][c]·W[o][c] + b[o]
    gemm256<2, false, bf16, false, 2, 64><<<256, 512, 0, stream>>>(
        ynT, 8388608, 512, wbf, 262144, 512, qT, 8388608, 512,
        bpk, 512, nullptr, 0, 1.f, nullptr);
    // v conv per batch: v[o][n] = wv[o][c]·hnT[n][c] + bv[o]
    gemm256<1, false, bf16, false, 4, 2><<<128, 512, 0, stream>>>(
        wbf + 2 * 262144, 0, 512, hnT, sBC, 512, v, sBC, 1024,
        bpk + 1024, 0, nullptr, 0, 1.f, nullptr);
    // QK^T + row stats: S = scl * qT·kT^T
    gemm256<0, false, float, true, 4, 4><<<256, 512, 0, stream>>>(
        qT, sBC, 512, kT, sBC, 512, S, 1048576, 1024,
        bpk, 0, nullptr, 0, scl, stats);
    // fused softmax + PV -> aoT [b][hw][c]
    pv_gemm<<<256, 512, 0, stream>>>(S, stats, v, aoT);
    // proj + bias + residual
    gemm256<1, true, float, false, 4, 2><<<128, 512, 0, stream>>>(
        wbf + 3 * 262144, 0, 512, aoT, sBC, 512, out, sBC, 1024,
        bpk + 1536, 0, x, sBC, 1.f, nullptr);
}

// Round 6
// 164.353 us; speedup vs baseline: 1.3346x; 1.1709x over previous
//
#include <hip/hip_runtime.h>
#include <hip/hip_bf16.h>

typedef __bf16 bf16;
typedef __bf16 bf16x8 __attribute__((ext_vector_type(8)));
typedef float f32x4 __attribute__((ext_vector_type(4)));
typedef unsigned short u16;
typedef unsigned short u16x8 __attribute__((ext_vector_type(8)));

constexpr int kHW = 1024;
constexpr int kC  = 512;
constexpr int kCPG = 16;

__device__ inline float wave_sum(float v) {
#pragma unroll
    for (int o = 32; o; o >>= 1) v += __shfl_xor(v, o, 64);
    return v;
}

__device__ inline float b2f(u16 u) {
    union { float f; unsigned i; } z; z.i = ((unsigned)u) << 16; return z.f;
}

__device__ inline void gload_lds16(const void* g, void* l) {
    __builtin_amdgcn_global_load_lds(
        (const __attribute__((address_space(1))) void*)g,
        (__attribute__((address_space(3))) void*)l, 16, 0, 0);
}

#define VMCNT(n) asm volatile("s_waitcnt vmcnt(" #n ")" ::: "memory")
#define SBAR __builtin_amdgcn_s_barrier()
#define NOP do {} while (0)

// ---------------- weights f32->bf16 + bias pack ----------------
__global__ __launch_bounds__(256) void wconv_kernel(
    const float* __restrict__ wq, const float* __restrict__ wk,
    const float* __restrict__ wv, const float* __restrict__ wp,
    const float* __restrict__ bq, const float* __restrict__ bk,
    const float* __restrict__ bv, const float* __restrict__ bp,
    bf16* __restrict__ dst, float* __restrict__ bpk)
{
    int i = blockIdx.x * 256 + threadIdx.x;
    dst[i]            = (bf16)wq[i];
    dst[262144 + i]   = (bf16)wk[i];
    dst[2*262144 + i] = (bf16)wv[i];
    dst[3*262144 + i] = (bf16)wp[i];
    if (i < 2048) {
        int j = i >> 9, c = i & 511;
        const float* s = j == 0 ? bq : j == 1 ? bk : j == 2 ? bv : bp;
        bpk[i] = s[c];
    }
}

// ---------------- 2x GroupNorm -> transposed bf16 [b][hw][c] --------------
__global__ __launch_bounds__(256) void gn2_kernel(
    const float* __restrict__ x0, const float* __restrict__ s0,
    const float* __restrict__ b0, bf16* __restrict__ o0,
    const float* __restrict__ x1, const float* __restrict__ s1,
    const float* __restrict__ b1, bf16* __restrict__ o1)
{
    int sel = blockIdx.x >> 9;
    int blk = blockIdx.x & 511;
    const float* x = sel ? x1 : x0;
    const float* scale = sel ? s1 : s0;
    const float* bias  = sel ? b1 : b0;
    bf16* outT = sel ? o1 : o0;

    int b = blk >> 5, g = blk & 31;
    int c0 = g * kCPG;
    const float* xg = x + ((size_t)b * kC + c0) * kHW;

    float s = 0.f, s2 = 0.f;
    const float4* xg4 = reinterpret_cast<const float4*>(xg);
#pragma unroll
    for (int i = 0; i < 16; ++i) {
        float4 v = xg4[threadIdx.x + i * 256];
        s  += v.x + v.y + v.z + v.w;
        s2 += v.x*v.x + v.y*v.y + v.z*v.z + v.w*v.w;
    }
    s = wave_sum(s); s2 = wave_sum(s2);
    __shared__ float red[8];
    int lane = threadIdx.x & 63, wid = threadIdx.x >> 6;
    if (!lane) { red[wid] = s; red[4 + wid] = s2; }
    __syncthreads();
    float ts = red[0] + red[1] + red[2] + red[3];
    float t2 = red[4] + red[5] + red[6] + red[7];
    float mean = ts * (1.f / 16384.f);
    float var  = t2 * (1.f / 16384.f) - mean * mean;
    float inv  = rsqrtf(var + 1e-6f);

    int ci = threadIdx.x & 15;
    float a  = inv * scale[c0 + ci];
    float bb = bias[c0 + ci] - mean * a;
#pragma unroll
    for (int i = 0; i < 64; ++i) {
        int f = threadIdx.x + i * 256;
        int sp = f >> 4;
        float v = xg[ci * kHW + sp];
        outT[((size_t)b * kHW + sp) * kC + c0 + ci] = (bf16)(v * a + bb);
    }
}

// ======== 256x256 8-phase NT GEMM, K=512. Schedule v2 =====================
// Per K-tile: 4 phases; staging 2 tiles ahead into phase-freed quarters:
//   ph2: A(T+2,{0,2})   (freed after ph1)
//   ph3: B(T+2,{0,1})   (B freed after ph2)
//   ph4: B(T+2,{2,3}) + A(T+2,{1,3}); close with vmcnt(8) (one tile's loads)
// STATS: write P = exp(alpha*acc - rowmax_block) bf16 + (M,L) per (row, bx).
template <int BIAS, bool RESID, typename OUT_T, bool STATS, int NBX, int NBY>
__global__ __launch_bounds__(512, 2) void gemm256(
    const bf16* __restrict__ Ab, size_t sA, int lda,
    const bf16* __restrict__ Bb, size_t sB, int ldb,
    OUT_T* __restrict__ Cb, size_t sC, int ldc,
    const float* __restrict__ biasB, int sBias,
    const float* __restrict__ residB, size_t sR,
    float alpha, float* __restrict__ statsOut)
{
    __shared__ u16 lds[65536];           // 128KB: A 8x8KB (2slot x 4q), B same
    constexpr int NT = 8;                // K = 512

    int bid = blockIdx.x, nwg = gridDim.x;
    int swz = (bid & 7) * (nwg >> 3) + (bid >> 3);
    int job = swz / (NBX * NBY), rem = swz % (NBX * NBY);
    int by = rem / NBX, bx = rem % NBX;
    int brow = by * 256, bcol = bx * 256;

    const u16* Au = reinterpret_cast<const u16*>(Ab + (size_t)job * sA);
    const u16* Bu = reinterpret_cast<const u16*>(Bb + (size_t)job * sB);

    int t = threadIdx.x;
    int lane = t & 63, w = t >> 6;
    int wm = w >> 2, wn = w & 3;
    int cc = lane & 15, nib = lane >> 4;

    int trow = t >> 3;                               // 0..63
    int gsrc = ((t & 7) ^ (trow & 7)) * 8;           // pre-swizzled src granule
    const u16* Asrc = Au + (size_t)(brow + trow) * lda + gsrc;
    const u16* Bsrc = Bu + (size_t)(bcol + trow) * ldb + gsrc;
    u16* LDSA = lds;
    u16* LDSB = lds + 32768;

#define STAGE_A(TL, Q) gload_lds16(Asrc + (size_t)(Q) * 64 * lda + (TL) * 64, \
                                   LDSA + (((TL)&1)*4 + (Q)) * 4096 + t * 8)
#define STAGE_B(TL, Q) gload_lds16(Bsrc + (size_t)(Q) * 64 * ldb + (TL) * 64, \
                                   LDSB + (((TL)&1)*4 + (Q)) * 4096 + t * 8)

    f32x4 acc[8][4] = {};
    bf16x8 afr[4][2], bfr[4][2];

#define PHASE(MH, NH, TL, STG, WTC)                                           \
  {                                                                           \
    if ((NH) == 0) {                                                          \
      _Pragma("unroll") for (int mi = 0; mi < 4; ++mi)                        \
      _Pragma("unroll") for (int kx = 0; kx < 2; ++kx)                        \
        afr[mi][kx] = *reinterpret_cast<const bf16x8*>(LDSA +                 \
            (((TL)&1)*4 + wm*2 + (MH)) * 4096 + (mi*16 + cc) * 64 +           \
            (((nib + kx*4) ^ (cc & 7)) * 8));                                 \
    }                                                                         \
    if ((MH) == 0) {                                                          \
      _Pragma("unroll") for (int ni = 0; ni < 2; ++ni)                        \
      _Pragma("unroll") for (int kx = 0; kx < 2; ++kx)                        \
        bfr[(NH)*2 + ni][kx] = *reinterpret_cast<const bf16x8*>(LDSB +        \
            (((TL)&1)*4 + wn) * 4096 + (((NH)*2 + ni)*16 + cc) * 64 +         \
            (((nib + kx*4) ^ (cc & 7)) * 8));                                 \
    }                                                                         \
    STG;                                                                      \
    SBAR;                                                                     \
    __builtin_amdgcn_s_setprio(1);                                            \
    _Pragma("unroll") for (int mi = 0; mi < 4; ++mi)                          \
    _Pragma("unroll") for (int ni = 0; ni < 2; ++ni)                          \
    _Pragma("unroll") for (int kx = 0; kx < 2; ++kx)                          \
      acc[(MH)*4 + mi][(NH)*2 + ni] = __builtin_amdgcn_mfma_f32_16x16x32_bf16(\
          afr[mi][kx], bfr[(NH)*2 + ni][kx], acc[(MH)*4 + mi][(NH)*2 + ni],   \
          0, 0, 0);                                                           \
    __builtin_amdgcn_s_setprio(0);                                            \
    WTC;                                                                      \
    SBAR;                                                                     \
  }

    // prologue: tiles 0 and 1 fully staged; wait for tile 0
    STAGE_A(0, 0); STAGE_A(0, 2); STAGE_B(0, 0); STAGE_B(0, 1);
    STAGE_B(0, 2); STAGE_B(0, 3); STAGE_A(0, 1); STAGE_A(0, 3);
    STAGE_A(1, 0); STAGE_A(1, 2); STAGE_B(1, 0); STAGE_B(1, 1);
    STAGE_B(1, 2); STAGE_B(1, 3); STAGE_A(1, 1); STAGE_A(1, 3);
    VMCNT(8);
    SBAR;

#pragma unroll
    for (int kt = 0; kt < NT; ++kt) {
        PHASE(0, 0, kt, NOP, NOP);
        PHASE(0, 1, kt,
              if (kt + 2 < NT) { STAGE_A(kt + 2, 0); STAGE_A(kt + 2, 2); },
              NOP);
        PHASE(1, 0, kt,
              if (kt + 2 < NT) { STAGE_B(kt + 2, 0); STAGE_B(kt + 2, 1); },
              NOP);
        PHASE(1, 1, kt,
              if (kt + 2 < NT) { STAGE_B(kt + 2, 2); STAGE_B(kt + 2, 3);
                                 STAGE_A(kt + 2, 1); STAGE_A(kt + 2, 3); },
              if (kt < NT - 2) { VMCNT(8); } else if (kt == NT - 2) { VMCNT(0); });
    }
#undef PHASE
#undef STAGE_A
#undef STAGE_B

#pragma unroll
    for (int m = 0; m < 8; ++m)
#pragma unroll
        for (int n = 0; n < 4; ++n)
#pragma unroll
            for (int r = 0; r < 4; ++r)
                acc[m][n][r] *= alpha;

    if constexpr (STATS) {
        float* sredM = reinterpret_cast<float*>(lds);          // [4][256]
        float* sredS = reinterpret_cast<float*>(lds) + 1024;   // [4][256]
        float rmax[8][4];
#pragma unroll
        for (int m = 0; m < 8; ++m)
#pragma unroll
            for (int r = 0; r < 4; ++r) {
                float v_ = fmaxf(fmaxf(acc[m][0][r], acc[m][1][r]),
                                 fmaxf(acc[m][2][r], acc[m][3][r]));
                v_ = fmaxf(v_, __shfl_xor(v_, 1, 64));
                v_ = fmaxf(v_, __shfl_xor(v_, 2, 64));
                v_ = fmaxf(v_, __shfl_xor(v_, 4, 64));
                v_ = fmaxf(v_, __shfl_xor(v_, 8, 64));
                rmax[m][r] = v_;
            }
        if (cc == 0)
#pragma unroll
            for (int m = 0; m < 8; ++m)
#pragma unroll
                for (int r = 0; r < 4; ++r)
                    sredM[wn * 256 + wm * 128 + m * 16 + nib * 4 + r] = rmax[m][r];
        __syncthreads();
#pragma unroll
        for (int m = 0; m < 8; ++m)
#pragma unroll
            for (int r = 0; r < 4; ++r) {
                int lr = wm * 128 + m * 16 + nib * 4 + r;
                rmax[m][r] = fmaxf(fmaxf(sredM[lr], sredM[256 + lr]),
                                   fmaxf(sredM[512 + lr], sredM[768 + lr]));
            }
        // transform acc -> P_local = exp(acc - rowmax), accumulate row sums
#pragma unroll
        for (int m = 0; m < 8; ++m)
#pragma unroll
            for (int r = 0; r < 4; ++r) {
                float s_ = 0.f;
#pragma unroll
                for (int n = 0; n < 4; ++n) {
                    float e = __expf(acc[m][n][r] - rmax[m][r]);
                    acc[m][n][r] = e;
                    s_ += e;
                }
                s_ += __shfl_xor(s_, 1, 64);
                s_ += __shfl_xor(s_, 2, 64);
                s_ += __shfl_xor(s_, 4, 64);
                s_ += __shfl_xor(s_, 8, 64);
                if (cc == 0)
                    sredS[wn * 256 + wm * 128 + m * 16 + nib * 4 + r] = s_;
            }
        __syncthreads();
        if (t < 256) {
            float M = fmaxf(fmaxf(sredM[t], sredM[256 + t]),
                            fmaxf(sredM[512 + t], sredM[768 + t]));
            float L = sredS[t] + sredS[256 + t] + sredS[512 + t] + sredS[768 + t];
            size_t off = ((size_t)(job * 1024 + brow + t)) * 8 + bx * 2;
            statsOut[off]     = M;
            statsOut[off + 1] = L;
        }
    }

    OUT_T* Cj = Cb + (size_t)job * sC;
    const float* bias = biasB + (size_t)job * sBias;
#pragma unroll
    for (int m = 0; m < 8; ++m) {
#pragma unroll
        for (int n = 0; n < 4; ++n) {
#pragma unroll
            for (int r = 0; r < 4; ++r) {
                int grow = brow + wm * 128 + m * 16 + nib * 4 + r;
                int gcol = bcol + wn * 64 + n * 16 + cc;
                float vv = acc[m][n][r];
                if (BIAS == 1) vv += bias[grow];
                if (BIAS == 2) vv += bias[gcol];
                if (RESID)     vv += residB[(size_t)job * sR + (size_t)grow * ldc + gcol];
                Cj[(size_t)grow * ldc + gcol] = (OUT_T)vv;
            }
        }
    }
}

// ======== 128x256 NT GEMM, BK=64, ring-3 slots, 1 barrier/tile ============
// For weight-A GEMMs (v conv, proj): A=W[512x512], B=[1024x512] per job.
template <int BIAS, bool RESID, typename OUT_T, int NBX, int NBY>
__global__ __launch_bounds__(512, 2) void gemm128(
    const bf16* __restrict__ Ab, size_t sA, int lda,
    const bf16* __restrict__ Bb, size_t sB, int ldb,
    OUT_T* __restrict__ Cb, size_t sC, int ldc,
    const float* __restrict__ biasB, int sBias,
    const float* __restrict__ residB, size_t sR)
{
    __shared__ u16 lds[3 * 24576];       // 144KB: 3 slots x (A 16KB + B 32KB)
    constexpr int NT = 8;

    int bid = blockIdx.x, nwg = gridDim.x;
    int swz = (bid & 7) * (nwg >> 3) + (bid >> 3);
    int job = swz / (NBX * NBY), rem = swz % (NBX * NBY);
    int by = rem / NBX, bx = rem % NBX;
    int brow = by * 128, bcol = bx * 256;

    const u16* Au = reinterpret_cast<const u16*>(Ab + (size_t)job * sA);
    const u16* Bu = reinterpret_cast<const u16*>(Bb + (size_t)job * sB);

    int t = threadIdx.x;
    int lane = t & 63, w = t >> 6;
    int wm = w >> 2, wn = w & 3;         // wm 0..1 (M), wn 0..3 (N)
    int cc = lane & 15, nib = lane >> 4;

    int trow = t >> 3;
    int gsrc = ((t & 7) ^ (trow & 7)) * 8;
    const u16* Asrc = Au + (size_t)(brow + trow) * lda + gsrc;
    const u16* Bsrc = Bu + (size_t)(bcol + trow) * ldb + gsrc;

#define STG_T(TL) {                                                           \
    u16* sl_ = lds + ((TL) % 3) * 24576;                                      \
    gload_lds16(Asrc + (TL) * 64,                          sl_ + t * 8);      \
    gload_lds16(Asrc + (size_t)64 * lda + (TL) * 64,       sl_ + 4096 + t*8); \
    gload_lds16(Bsrc + (TL) * 64,                          sl_ + 8192 + t*8); \
    gload_lds16(Bsrc + (size_t)64  * ldb + (TL) * 64,      sl_ + 12288 + t*8);\
    gload_lds16(Bsrc + (size_t)128 * ldb + (TL) * 64,      sl_ + 16384 + t*8);\
    gload_lds16(Bsrc + (size_t)192 * ldb + (TL) * 64,      sl_ + 20480 + t*8);\
  }

    f32x4 acc[4][4] = {};

    STG_T(0); STG_T(1);
    VMCNT(6);
    SBAR;

#pragma unroll
    for (int kt = 0; kt < NT; ++kt) {
        if (kt + 2 < NT) STG_T(kt + 2);
        const u16* sb = lds + (kt % 3) * 24576;
        bf16x8 a[4][2], b[4][2];
#pragma unroll
        for (int mi = 0; mi < 4; ++mi)
#pragma unroll
            for (int kx = 0; kx < 2; ++kx)
                a[mi][kx] = *reinterpret_cast<const bf16x8*>(sb +
                    wm * 4096 + (mi*16 + cc) * 64 + (((nib + kx*4) ^ (cc & 7)) * 8));
#pragma unroll
        for (int ni = 0; ni < 4; ++ni)
#pragma unroll
            for (int kx = 0; kx < 2; ++kx)
                b[ni][kx] = *reinterpret_cast<const bf16x8*>(sb + 8192 +
                    wn * 4096 + (ni*16 + cc) * 64 + (((nib + kx*4) ^ (cc & 7)) * 8));
        __builtin_amdgcn_s_setprio(1);
#pragma unroll
        for (int mi = 0; mi < 4; ++mi)
#pragma unroll
            for (int ni = 0; ni < 4; ++ni)
#pragma unroll
                for (int kx = 0; kx < 2; ++kx)
                    acc[mi][ni] = __builtin_amdgcn_mfma_f32_16x16x32_bf16(
                        a[mi][kx], b[ni][kx], acc[mi][ni], 0, 0, 0);
        __builtin_amdgcn_s_setprio(0);
        if (kt < NT - 2) { VMCNT(6); } else if (kt == NT - 2) { VMCNT(0); }
        SBAR;
    }
#undef STG_T

    OUT_T* Cj = Cb + (size_t)job * sC;
    const float* bias = biasB + (size_t)job * sBias;
#pragma unroll
    for (int mi = 0; mi < 4; ++mi) {
#pragma unroll
        for (int ni = 0; ni < 4; ++ni) {
#pragma unroll
            for (int r = 0; r < 4; ++r) {
                int grow = brow + wm * 64 + mi * 16 + nib * 4 + r;
                int gcol = bcol + wn * 64 + ni * 16 + cc;
                float vv = acc[mi][ni][r];
                if (BIAS == 1) vv += bias[grow];
                if (BIAS == 2) vv += bias[gcol];
                if (RESID)     vv += residB[(size_t)job * sR + (size_t)grow * ldc + gcol];
                Cj[(size_t)grow * ldc + gcol] = (OUT_T)vv;
            }
        }
    }
}

// ======== PV: O = (P_local * alpha_blk) . V^T / L ==========================
// BM=128(i) x BN=256(c), BK=32(j). P bf16 in, alpha-rescale at staging.
// Double-buffered LDS, XOR-swizzled (conflict-free), T14 load-early/write-late.
__global__ __launch_bounds__(512, 2) void pv_gemm(
    const bf16* __restrict__ P, const float* __restrict__ stats,
    const bf16* __restrict__ V, bf16* __restrict__ O)
{
    __shared__ u16 ldsA[2][4096];        // 128 x 32
    __shared__ u16 ldsB[2][8192];        // 256 x 32
    __shared__ float Ml[128], Ll[128], Mb[4][128];

    int bid = blockIdx.x;
    int swz = (bid & 7) * 32 + (bid >> 3);       // nwg = 256
    int job = swz >> 4, rem = swz & 15;
    int by = rem >> 1, bx = rem & 1;             // 8 x 2 tiles
    int brow = by * 128, bcol = bx * 256;

    int t = threadIdx.x;
    int lane = t & 63, w = t >> 6;
    int wm = w >> 2, wn = w & 3;
    int cc = lane & 15, nib = lane >> 4;

    if (t < 128) {
        const float* st = stats + ((size_t)(job * 1024 + brow + t)) * 8;
        float M = st[0];
#pragma unroll
        for (int k = 1; k < 4; ++k) M = fmaxf(M, st[2 * k]);
        float L = 0.f;
#pragma unroll
        for (int k = 0; k < 4; ++k) L += st[2 * k + 1] * __expf(st[2 * k] - M);
        Ml[t] = M; Ll[t] = L;
        Mb[0][t] = st[0]; Mb[1][t] = st[2]; Mb[2][t] = st[4]; Mb[3][t] = st[6];
    }
    __syncthreads();

    int ar = t >> 2, ag = t & 3;                 // A: row, col-group
    int asw = ((ag ^ ((ar >> 1) & 3))) * 8;      // swizzled write col
    float alf[4];
#pragma unroll
    for (int k = 0; k < 4; ++k) alf[k] = __expf(Mb[k][ar] - Ml[ar]);

    const u16* Pr = reinterpret_cast<const u16*>(P) + (size_t)job * 1048576
                    + (size_t)(brow + ar) * 1024 + ag * 8;
    int br = t >> 1;
    const u16* Vr = reinterpret_cast<const u16*>(V) + (size_t)job * 524288
                    + (size_t)(bcol + br) * 1024 + (t & 1) * 16;
    int bg0 = (t & 1) * 2, bg1 = bg0 + 1;
    int bsw0 = (bg0 ^ ((br >> 1) & 3)) * 8;
    int bsw1 = (bg1 ^ ((br >> 1) & 3)) * 8;
    int rsw = (nib ^ ((cc >> 1) & 3)) * 8;       // swizzled read col

    f32x4 acc[4][4] = {};

    // prologue: stage step 0 into slot 0
    {
        u16x8 p8 = *reinterpret_cast<const u16x8*>(Pr);
        u16x8 v0 = *reinterpret_cast<const u16x8*>(Vr);
        u16x8 v1 = *reinterpret_cast<const u16x8*>(Vr + 8);
        float af = alf[0];
        bf16x8 pw;
#pragma unroll
        for (int j = 0; j < 8; ++j) pw[j] = (bf16)(b2f(p8[j]) * af);
        *reinterpret_cast<bf16x8*>(&ldsA[0][ar * 32 + asw]) = pw;
        *reinterpret_cast<u16x8*>(&ldsB[0][br * 32 + bsw0]) = v0;
        *reinterpret_cast<u16x8*>(&ldsB[0][br * 32 + bsw1]) = v1;
    }
    __syncthreads();

#pragma unroll
    for (int kt = 0; kt < 32; ++kt) {
        int cur = kt & 1;
        u16x8 p8, v0, v1;
        if (kt < 31) {                            // T14: issue loads early
            p8 = *reinterpret_cast<const u16x8*>(Pr + (kt + 1) * 32);
            v0 = *reinterpret_cast<const u16x8*>(Vr + (kt + 1) * 32);
            v1 = *reinterpret_cast<const u16x8*>(Vr + (kt + 1) * 32 + 8);
        }
        bf16x8 a[4], b[4];
#pragma unroll
        for (int mi = 0; mi < 4; ++mi)
            a[mi] = *reinterpret_cast<const bf16x8*>(
                &ldsA[cur][(wm * 64 + mi * 16 + cc) * 32 + rsw]);
#pragma unroll
        for (int ni = 0; ni < 4; ++ni)
            b[ni] = *reinterpret_cast<const bf16x8*>(
                &ldsB[cur][(wn * 64 + ni * 16 + cc) * 32 + rsw]);
        __builtin_amdgcn_s_setprio(1);
#pragma unroll
        for (int mi = 0; mi < 4; ++mi)
#pragma unroll
            for (int ni = 0; ni < 4; ++ni)
                acc[mi][ni] = __builtin_amdgcn_mfma_f32_16x16x32_bf16(
                    a[mi], b[ni], acc[mi][ni], 0, 0, 0);
        __builtin_amdgcn_s_setprio(0);
        if (kt < 31) {                            // write-late into other slot
            float af = alf[(kt + 1) >> 3];
            bf16x8 pw;
#pragma unroll
            for (int j = 0; j < 8; ++j) pw[j] = (bf16)(b2f(p8[j]) * af);
            *reinterpret_cast<bf16x8*>(&ldsA[cur ^ 1][ar * 32 + asw]) = pw;
            *reinterpret_cast<u16x8*>(&ldsB[cur ^ 1][br * 32 + bsw0]) = v0;
            *reinterpret_cast<u16x8*>(&ldsB[cur ^ 1][br * 32 + bsw1]) = v1;
        }
        __syncthreads();
    }

    bf16* Oj = O + (size_t)job * 524288;
#pragma unroll
    for (int mi = 0; mi < 4; ++mi) {
#pragma unroll
        for (int r = 0; r < 4; ++r) {
            int lr = wm * 64 + mi * 16 + nib * 4 + r;
            float linv = 1.0f / Ll[lr];
#pragma unroll
            for (int ni = 0; ni < 4; ++ni) {
                int gcol = bcol + wn * 64 + ni * 16 + cc;
                Oj[(size_t)(brow + lr) * 512 + gcol] = (bf16)(acc[mi][ni][r] * linv);
            }
        }
    }
}

extern "C" void kernel_launch(void* const* d_in, const int* in_sizes, int n_in,
                              void* d_out, int out_size, void* d_ws, size_t ws_size,
                              hipStream_t stream)
{
    const float* x   = (const float*)d_in[0];
    const float* y   = (const float*)d_in[1];
    const float* ns  = (const float*)d_in[2];
    const float* nb  = (const float*)d_in[3];
    const float* n1s = (const float*)d_in[4];
    const float* n1b = (const float*)d_in[5];
    const float* wq  = (const float*)d_in[6];
    const float* bq  = (const float*)d_in[7];
    const float* wk  = (const float*)d_in[8];
    const float* bk  = (const float*)d_in[9];
    const float* wv  = (const float*)d_in[10];
    const float* bv  = (const float*)d_in[11];
    const float* wp  = (const float*)d_in[12];
    const float* bp  = (const float*)d_in[13];
    float* out = (float*)d_out;

    char* ws = (char*)d_ws;
    bf16* wbf  = (bf16*)ws;                          // 2 MB weights bf16
    float* bpk = (float*)(ws + 2097152);             // 8 KB biases
    bf16* ynT = (bf16*)(ws + 2105344);               // [b][hw][c]
    bf16* hnT = ynT + 8388608;
    bf16* qT  = hnT + 8388608;
    bf16* kT  = qT  + 8388608;
    bf16* v   = kT  + 8388608;                       // [b][c][hw]
    float* stats = (float*)ynT;                      // ynT dead after q/k conv
    bf16* aoT = qT;                                  // qT dead after QK^T
    bf16* P   = (bf16*)(ws + 2105344 + 5ull * 16777216);   // 32 MB bf16

    const size_t sBC = (size_t)kHW * kC;
    const float scl = 0.044194173824159216f;         // 512^-0.5

    wconv_kernel<<<1024, 256, 0, stream>>>(wq, wk, wv, wp, bq, bk, bv, bp, wbf, bpk);
    gn2_kernel<<<1024, 256, 0, stream>>>(x, ns, nb, hnT, y, n1s, n1b, ynT);

    // q & k convs fused (jobs 0/1): out_T[i][o] = in_T[i][c]·W[o][c] + b[o]
    gemm256<2, false, bf16, false, 2, 64><<<256, 512, 0, stream>>>(
        ynT, 8388608, 512, wbf, 262144, 512, qT, 8388608, 512,
        bpk, 512, nullptr, 0, 1.f, nullptr);
    // v conv per batch: v[o][n] = wv[o][c]·hnT[n][c] + bv[o]
    gemm128<1, false, bf16, 4, 4><<<256, 512, 0, stream>>>(
        wbf + 2 * 262144, 0, 512, hnT, sBC, 512, v, sBC, 1024,
        bpk + 1024, 0, nullptr, 0);
    // QK^T -> P_local bf16 + (M,L) stats per (row, bx)
    gemm256<0, false, bf16, true, 4, 4><<<256, 512, 0, stream>>>(
        qT, sBC, 512, kT, sBC, 512, P, 1048576, 1024,
        bpk, 0, nullptr, 0, scl, stats);
    // fused softmax-finish + PV -> aoT [b][hw][c]
    pv_gemm<<<256, 512, 0, stream>>>(P, stats, v, aoT);
    // proj + bias + residual
    gemm128<1, true, float, 4, 4><<<256, 512, 0, stream>>>(
        wbf + 3 * 262144, 0, 512, aoT, sBC, 512, out, sBC, 1024,
        bpk + 1536, 0, x, sBC);
}

// Round 7
// 146.264 us; speedup vs baseline: 1.4997x; 1.1237x over previous
//
#include <hip/hip_runtime.h>
#include <hip/hip_bf16.h>

typedef __bf16 bf16;
typedef __bf16 bf16x8 __attribute__((ext_vector_type(8)));
typedef __bf16 bf16x4 __attribute__((ext_vector_type(4)));
typedef float f32x4 __attribute__((ext_vector_type(4)));
typedef unsigned short u16;
typedef unsigned short u16x8 __attribute__((ext_vector_type(8)));

constexpr int kHW = 1024;
constexpr int kC  = 512;
constexpr int kCPG = 16;

__device__ inline float wave_sum(float v) {
#pragma unroll
    for (int o = 32; o; o >>= 1) v += __shfl_xor(v, o, 64);
    return v;
}

__device__ inline float b2f(u16 u) {
    union { float f; unsigned i; } z; z.i = ((unsigned)u) << 16; return z.f;
}

__device__ inline void gload_lds16(const void* g, void* l) {
    __builtin_amdgcn_global_load_lds(
        (const __attribute__((address_space(1))) void*)g,
        (__attribute__((address_space(3))) void*)l, 16, 0, 0);
}

#define VMCNT(n) asm volatile("s_waitcnt vmcnt(" #n ")" ::: "memory")
#define SBAR __builtin_amdgcn_s_barrier()
#define NOP do {} while (0)

// ---------------- weights f32->bf16 + bias pack ----------------
__global__ __launch_bounds__(256) void wconv_kernel(
    const float* __restrict__ wq, const float* __restrict__ wk,
    const float* __restrict__ wv, const float* __restrict__ wp,
    const float* __restrict__ bq, const float* __restrict__ bk,
    const float* __restrict__ bv, const float* __restrict__ bp,
    bf16* __restrict__ dst, float* __restrict__ bpk)
{
    int i = blockIdx.x * 256 + threadIdx.x;
    dst[i]            = (bf16)wq[i];
    dst[262144 + i]   = (bf16)wk[i];
    dst[2*262144 + i] = (bf16)wv[i];
    dst[3*262144 + i] = (bf16)wp[i];
    if (i < 2048) {
        int j = i >> 9, c = i & 511;
        const float* s = j == 0 ? bq : j == 1 ? bk : j == 2 ? bv : bp;
        bpk[i] = s[c];
    }
}

// ---------------- 2x GroupNorm -> transposed bf16 [b][hw][c] --------------
// LDS-staged: pass-1 coalesced global read fills xs[16][1028] (pad 4 ->
// 2-way banks, free); pass-2 reads LDS and writes bf16x4 transposed.
__global__ __launch_bounds__(256) void gn2_kernel(
    const float* __restrict__ x0, const float* __restrict__ s0,
    const float* __restrict__ b0, bf16* __restrict__ o0,
    const float* __restrict__ x1, const float* __restrict__ s1,
    const float* __restrict__ b1, bf16* __restrict__ o1)
{
    __shared__ float xs[16][1028];
    __shared__ float red[8];
    __shared__ float ab[2][16];

    int sel = blockIdx.x >> 9;
    int blk = blockIdx.x & 511;
    const float* x = sel ? x1 : x0;
    const float* scale = sel ? s1 : s0;
    const float* bias  = sel ? b1 : b0;
    bf16* outT = sel ? o1 : o0;

    int b = blk >> 5, g = blk & 31;
    int c0 = g * kCPG;
    const float* xg = x + ((size_t)b * kC + c0) * kHW;

    int t = threadIdx.x;
    float s = 0.f, s2 = 0.f;
    const float4* xg4 = reinterpret_cast<const float4*>(xg);
#pragma unroll
    for (int i = 0; i < 16; ++i) {
        float4 v = xg4[t + i * 256];              // row i, col 4t
        *reinterpret_cast<float4*>(&xs[i][t * 4]) = v;
        s  += v.x + v.y + v.z + v.w;
        s2 += v.x*v.x + v.y*v.y + v.z*v.z + v.w*v.w;
    }
    s = wave_sum(s); s2 = wave_sum(s2);
    int lane = t & 63, wid = t >> 6;
    if (!lane) { red[wid] = s; red[4 + wid] = s2; }
    __syncthreads();
    float ts = red[0] + red[1] + red[2] + red[3];
    float t2 = red[4] + red[5] + red[6] + red[7];
    float mean = ts * (1.f / 16384.f);
    float var  = t2 * (1.f / 16384.f) - mean * mean;
    float inv  = rsqrtf(var + 1e-6f);

    if (t < 16) {
        float a = inv * scale[c0 + t];
        ab[0][t] = a;
        ab[1][t] = bias[c0 + t] - mean * a;
    }
    __syncthreads();

    int cg = t & 3, spw = t >> 2;                 // 4 channel-groups x 64 rows
    float a0 = ab[0][cg*4],   a1 = ab[0][cg*4+1],
          a2 = ab[0][cg*4+2], a3 = ab[0][cg*4+3];
    float d0 = ab[1][cg*4],   d1 = ab[1][cg*4+1],
          d2 = ab[1][cg*4+2], d3 = ab[1][cg*4+3];
    bf16* ob = outT + (size_t)b * kHW * kC + c0 + cg * 4;
#pragma unroll
    for (int i = 0; i < 16; ++i) {
        int sp = spw + i * 64;
        bf16x4 w;
        w[0] = (bf16)(xs[cg*4 + 0][sp] * a0 + d0);
        w[1] = (bf16)(xs[cg*4 + 1][sp] * a1 + d1);
        w[2] = (bf16)(xs[cg*4 + 2][sp] * a2 + d2);
        w[3] = (bf16)(xs[cg*4 + 3][sp] * a3 + d3);
        *reinterpret_cast<bf16x4*>(ob + (size_t)sp * kC) = w;
    }
}

// ======== 256x256 8-phase NT GEMM, K=512. Schedule v2 =====================
template <int BIAS, bool RESID, typename OUT_T, bool STATS, int NBX, int NBY>
__global__ __launch_bounds__(512, 2) void gemm256(
    const bf16* __restrict__ Ab, size_t sA, int lda,
    const bf16* __restrict__ Bb, size_t sB, int ldb,
    OUT_T* __restrict__ Cb, size_t sC, int ldc,
    const float* __restrict__ biasB, int sBias,
    const float* __restrict__ residB, size_t sR,
    float alpha, float* __restrict__ statsOut)
{
    __shared__ u16 lds[65536];           // 128KB: A 8x8KB (2slot x 4q), B same
    constexpr int NT = 8;                // K = 512

    int bid = blockIdx.x, nwg = gridDim.x;
    int swz = (bid & 7) * (nwg >> 3) + (bid >> 3);
    int job = swz / (NBX * NBY), rem = swz % (NBX * NBY);
    int by = rem / NBX, bx = rem % NBX;
    int brow = by * 256, bcol = bx * 256;

    const u16* Au = reinterpret_cast<const u16*>(Ab + (size_t)job * sA);
    const u16* Bu = reinterpret_cast<const u16*>(Bb + (size_t)job * sB);

    int t = threadIdx.x;
    int lane = t & 63, w = t >> 6;
    int wm = w >> 2, wn = w & 3;
    int cc = lane & 15, nib = lane >> 4;

    int trow = t >> 3;                               // 0..63
    int gsrc = ((t & 7) ^ (trow & 7)) * 8;           // pre-swizzled src granule
    const u16* Asrc = Au + (size_t)(brow + trow) * lda + gsrc;
    const u16* Bsrc = Bu + (size_t)(bcol + trow) * ldb + gsrc;
    u16* LDSA = lds;
    u16* LDSB = lds + 32768;

#define STAGE_A(TL, Q) gload_lds16(Asrc + (size_t)(Q) * 64 * lda + (TL) * 64, \
                                   LDSA + (((TL)&1)*4 + (Q)) * 4096 + t * 8)
#define STAGE_B(TL, Q) gload_lds16(Bsrc + (size_t)(Q) * 64 * ldb + (TL) * 64, \
                                   LDSB + (((TL)&1)*4 + (Q)) * 4096 + t * 8)

    f32x4 acc[8][4] = {};
    bf16x8 afr[4][2], bfr[4][2];

#define PHASE(MH, NH, TL, STG, WTC)                                           \
  {                                                                           \
    if ((NH) == 0) {                                                          \
      _Pragma("unroll") for (int mi = 0; mi < 4; ++mi)                        \
      _Pragma("unroll") for (int kx = 0; kx < 2; ++kx)                        \
        afr[mi][kx] = *reinterpret_cast<const bf16x8*>(LDSA +                 \
            (((TL)&1)*4 + wm*2 + (MH)) * 4096 + (mi*16 + cc) * 64 +           \
            (((nib + kx*4) ^ (cc & 7)) * 8));                                 \
    }                                                                         \
    if ((MH) == 0) {                                                          \
      _Pragma("unroll") for (int ni = 0; ni < 2; ++ni)                        \
      _Pragma("unroll") for (int kx = 0; kx < 2; ++kx)                        \
        bfr[(NH)*2 + ni][kx] = *reinterpret_cast<const bf16x8*>(LDSB +        \
            (((TL)&1)*4 + wn) * 4096 + (((NH)*2 + ni)*16 + cc) * 64 +         \
            (((nib + kx*4) ^ (cc & 7)) * 8));                                 \
    }                                                                         \
    STG;                                                                      \
    SBAR;                                                                     \
    __builtin_amdgcn_s_setprio(1);                                            \
    _Pragma("unroll") for (int mi = 0; mi < 4; ++mi)                          \
    _Pragma("unroll") for (int ni = 0; ni < 2; ++ni)                          \
    _Pragma("unroll") for (int kx = 0; kx < 2; ++kx)                          \
      acc[(MH)*4 + mi][(NH)*2 + ni] = __builtin_amdgcn_mfma_f32_16x16x32_bf16(\
          afr[mi][kx], bfr[(NH)*2 + ni][kx], acc[(MH)*4 + mi][(NH)*2 + ni],   \
          0, 0, 0);                                                           \
    __builtin_amdgcn_s_setprio(0);                                            \
    WTC;                                                                      \
    SBAR;                                                                     \
  }

    // prologue: tiles 0 and 1 fully staged; wait for tile 0
    STAGE_A(0, 0); STAGE_A(0, 2); STAGE_B(0, 0); STAGE_B(0, 1);
    STAGE_B(0, 2); STAGE_B(0, 3); STAGE_A(0, 1); STAGE_A(0, 3);
    STAGE_A(1, 0); STAGE_A(1, 2); STAGE_B(1, 0); STAGE_B(1, 1);
    STAGE_B(1, 2); STAGE_B(1, 3); STAGE_A(1, 1); STAGE_A(1, 3);
    VMCNT(8);
    SBAR;

#pragma unroll
    for (int kt = 0; kt < NT; ++kt) {
        PHASE(0, 0, kt, NOP, NOP);
        PHASE(0, 1, kt,
              if (kt + 2 < NT) { STAGE_A(kt + 2, 0); STAGE_A(kt + 2, 2); },
              NOP);
        PHASE(1, 0, kt,
              if (kt + 2 < NT) { STAGE_B(kt + 2, 0); STAGE_B(kt + 2, 1); },
              NOP);
        PHASE(1, 1, kt,
              if (kt + 2 < NT) { STAGE_B(kt + 2, 2); STAGE_B(kt + 2, 3);
                                 STAGE_A(kt + 2, 1); STAGE_A(kt + 2, 3); },
              if (kt < NT - 2) { VMCNT(8); } else if (kt == NT - 2) { VMCNT(0); });
    }
#undef PHASE
#undef STAGE_A
#undef STAGE_B

#pragma unroll
    for (int m = 0; m < 8; ++m)
#pragma unroll
        for (int n = 0; n < 4; ++n)
#pragma unroll
            for (int r = 0; r < 4; ++r)
                acc[m][n][r] *= alpha;

    if constexpr (STATS) {
        float* sredM = reinterpret_cast<float*>(lds);          // [4][256]
        float* sredS = reinterpret_cast<float*>(lds) + 1024;   // [4][256]
        float rmax[8][4];
#pragma unroll
        for (int m = 0; m < 8; ++m)
#pragma unroll
            for (int r = 0; r < 4; ++r) {
                float v_ = fmaxf(fmaxf(acc[m][0][r], acc[m][1][r]),
                                 fmaxf(acc[m][2][r], acc[m][3][r]));
                v_ = fmaxf(v_, __shfl_xor(v_, 1, 64));
                v_ = fmaxf(v_, __shfl_xor(v_, 2, 64));
                v_ = fmaxf(v_, __shfl_xor(v_, 4, 64));
                v_ = fmaxf(v_, __shfl_xor(v_, 8, 64));
                rmax[m][r] = v_;
            }
        if (cc == 0)
#pragma unroll
            for (int m = 0; m < 8; ++m)
#pragma unroll
                for (int r = 0; r < 4; ++r)
                    sredM[wn * 256 + wm * 128 + m * 16 + nib * 4 + r] = rmax[m][r];
        __syncthreads();
#pragma unroll
        for (int m = 0; m < 8; ++m)
#pragma unroll
            for (int r = 0; r < 4; ++r) {
                int lr = wm * 128 + m * 16 + nib * 4 + r;
                rmax[m][r] = fmaxf(fmaxf(sredM[lr], sredM[256 + lr]),
                                   fmaxf(sredM[512 + lr], sredM[768 + lr]));
            }
#pragma unroll
        for (int m = 0; m < 8; ++m)
#pragma unroll
            for (int r = 0; r < 4; ++r) {
                float s_ = 0.f;
#pragma unroll
                for (int n = 0; n < 4; ++n) {
                    float e = __expf(acc[m][n][r] - rmax[m][r]);
                    acc[m][n][r] = e;
                    s_ += e;
                }
                s_ += __shfl_xor(s_, 1, 64);
                s_ += __shfl_xor(s_, 2, 64);
                s_ += __shfl_xor(s_, 4, 64);
                s_ += __shfl_xor(s_, 8, 64);
                if (cc == 0)
                    sredS[wn * 256 + wm * 128 + m * 16 + nib * 4 + r] = s_;
            }
        __syncthreads();
        if (t < 256) {
            float M = fmaxf(fmaxf(sredM[t], sredM[256 + t]),
                            fmaxf(sredM[512 + t], sredM[768 + t]));
            float L = sredS[t] + sredS[256 + t] + sredS[512 + t] + sredS[768 + t];
            size_t off = ((size_t)(job * 1024 + brow + t)) * 8 + bx * 2;
            statsOut[off]     = M;
            statsOut[off + 1] = L;
        }
    }

    OUT_T* Cj = Cb + (size_t)job * sC;
    const float* bias = biasB + (size_t)job * sBias;
#pragma unroll
    for (int m = 0; m < 8; ++m) {
#pragma unroll
        for (int n = 0; n < 4; ++n) {
#pragma unroll
            for (int r = 0; r < 4; ++r) {
                int grow = brow + wm * 128 + m * 16 + nib * 4 + r;
                int gcol = bcol + wn * 64 + n * 16 + cc;
                float vv = acc[m][n][r];
                if (BIAS == 1) vv += bias[grow];
                if (BIAS == 2) vv += bias[gcol];
                if (RESID)     vv += residB[(size_t)job * sR + (size_t)grow * ldc + gcol];
                Cj[(size_t)grow * ldc + gcol] = (OUT_T)vv;
            }
        }
    }
}

// ======== 128x256 NT GEMM, BK=64, ring-3 slots, 1 barrier/tile ============
template <int BIAS, bool RESID, typename OUT_T, int NBX, int NBY>
__global__ __launch_bounds__(512, 2) void gemm128(
    const bf16* __restrict__ Ab, size_t sA, int lda,
    const bf16* __restrict__ Bb, size_t sB, int ldb,
    OUT_T* __restrict__ Cb, size_t sC, int ldc,
    const float* __restrict__ biasB, int sBias,
    const float* __restrict__ residB, size_t sR)
{
    __shared__ u16 lds[3 * 24576];       // 144KB: 3 slots x (A 16KB + B 32KB)
    constexpr int NT = 8;

    int bid = blockIdx.x, nwg = gridDim.x;
    int swz = (bid & 7) * (nwg >> 3) + (bid >> 3);
    int job = swz / (NBX * NBY), rem = swz % (NBX * NBY);
    int by = rem / NBX, bx = rem % NBX;
    int brow = by * 128, bcol = bx * 256;

    const u16* Au = reinterpret_cast<const u16*>(Ab + (size_t)job * sA);
    const u16* Bu = reinterpret_cast<const u16*>(Bb + (size_t)job * sB);

    int t = threadIdx.x;
    int lane = t & 63, w = t >> 6;
    int wm = w >> 2, wn = w & 3;         // wm 0..1 (M), wn 0..3 (N)
    int cc = lane & 15, nib = lane >> 4;

    int trow = t >> 3;
    int gsrc = ((t & 7) ^ (trow & 7)) * 8;
    const u16* Asrc = Au + (size_t)(brow + trow) * lda + gsrc;
    const u16* Bsrc = Bu + (size_t)(bcol + trow) * ldb + gsrc;

#define STG_T(TL) {                                                           \
    u16* sl_ = lds + ((TL) % 3) * 24576;                                      \
    gload_lds16(Asrc + (TL) * 64,                          sl_ + t * 8);      \
    gload_lds16(Asrc + (size_t)64 * lda + (TL) * 64,       sl_ + 4096 + t*8); \
    gload_lds16(Bsrc + (TL) * 64,                          sl_ + 8192 + t*8); \
    gload_lds16(Bsrc + (size_t)64  * ldb + (TL) * 64,      sl_ + 12288 + t*8);\
    gload_lds16(Bsrc + (size_t)128 * ldb + (TL) * 64,      sl_ + 16384 + t*8);\
    gload_lds16(Bsrc + (size_t)192 * ldb + (TL) * 64,      sl_ + 20480 + t*8);\
  }

    f32x4 acc[4][4] = {};

    STG_T(0); STG_T(1);
    VMCNT(6);
    SBAR;

#pragma unroll
    for (int kt = 0; kt < NT; ++kt) {
        if (kt + 2 < NT) STG_T(kt + 2);
        const u16* sb = lds + (kt % 3) * 24576;
        bf16x8 a[4][2], b[4][2];
#pragma unroll
        for (int mi = 0; mi < 4; ++mi)
#pragma unroll
            for (int kx = 0; kx < 2; ++kx)
                a[mi][kx] = *reinterpret_cast<const bf16x8*>(sb +
                    wm * 4096 + (mi*16 + cc) * 64 + (((nib + kx*4) ^ (cc & 7)) * 8));
#pragma unroll
        for (int ni = 0; ni < 4; ++ni)
#pragma unroll
            for (int kx = 0; kx < 2; ++kx)
                b[ni][kx] = *reinterpret_cast<const bf16x8*>(sb + 8192 +
                    wn * 4096 + (ni*16 + cc) * 64 + (((nib + kx*4) ^ (cc & 7)) * 8));
        __builtin_amdgcn_s_setprio(1);
#pragma unroll
        for (int mi = 0; mi < 4; ++mi)
#pragma unroll
            for (int ni = 0; ni < 4; ++ni)
#pragma unroll
                for (int kx = 0; kx < 2; ++kx)
                    acc[mi][ni] = __builtin_amdgcn_mfma_f32_16x16x32_bf16(
                        a[mi][kx], b[ni][kx], acc[mi][ni], 0, 0, 0);
        __builtin_amdgcn_s_setprio(0);
        if (kt < NT - 2) { VMCNT(6); } else if (kt == NT - 2) { VMCNT(0); }
        SBAR;
    }
#undef STG_T

    OUT_T* Cj = Cb + (size_t)job * sC;
    const float* bias = biasB + (size_t)job * sBias;
#pragma unroll
    for (int mi = 0; mi < 4; ++mi) {
#pragma unroll
        for (int ni = 0; ni < 4; ++ni) {
#pragma unroll
            for (int r = 0; r < 4; ++r) {
                int grow = brow + wm * 64 + mi * 16 + nib * 4 + r;
                int gcol = bcol + wn * 64 + ni * 16 + cc;
                float vv = acc[mi][ni][r];
                if (BIAS == 1) vv += bias[grow];
                if (BIAS == 2) vv += bias[gcol];
                if (RESID)     vv += residB[(size_t)job * sR + (size_t)grow * ldc + gcol];
                Cj[(size_t)grow * ldc + gcol] = (OUT_T)vv;
            }
        }
    }
}

// ======== PV: O = (P_local * alpha_blk) . V^T / L ==========================
__global__ __launch_bounds__(512, 2) void pv_gemm(
    const bf16* __restrict__ P, const float* __restrict__ stats,
    const bf16* __restrict__ V, bf16* __restrict__ O)
{
    __shared__ u16 ldsA[2][4096];        // 128 x 32
    __shared__ u16 ldsB[2][8192];        // 256 x 32
    __shared__ float Ml[128], Ll[128], Mb[4][128];

    int bid = blockIdx.x;
    int swz = (bid & 7) * 32 + (bid >> 3);       // nwg = 256
    int job = swz >> 4, rem = swz & 15;
    int by = rem >> 1, bx = rem & 1;             // 8 x 2 tiles
    int brow = by * 128, bcol = bx * 256;

    int t = threadIdx.x;
    int lane = t & 63, w = t >> 6;
    int wm = w >> 2, wn = w & 3;
    int cc = lane & 15, nib = lane >> 4;

    if (t < 128) {
        const float* st = stats + ((size_t)(job * 1024 + brow + t)) * 8;
        float M = st[0];
#pragma unroll
        for (int k = 1; k < 4; ++k) M = fmaxf(M, st[2 * k]);
        float L = 0.f;
#pragma unroll
        for (int k = 0; k < 4; ++k) L += st[2 * k + 1] * __expf(st[2 * k] - M);
        Ml[t] = M; Ll[t] = L;
        Mb[0][t] = st[0]; Mb[1][t] = st[2]; Mb[2][t] = st[4]; Mb[3][t] = st[6];
    }
    __syncthreads();

    int ar = t >> 2, ag = t & 3;                 // A: row, col-group
    int asw = ((ag ^ ((ar >> 1) & 3))) * 8;      // swizzled write col
    float alf[4];
#pragma unroll
    for (int k = 0; k < 4; ++k) alf[k] = __expf(Mb[k][ar] - Ml[ar]);

    const u16* Pr = reinterpret_cast<const u16*>(P) + (size_t)job * 1048576
                    + (size_t)(brow + ar) * 1024 + ag * 8;
    int br = t >> 1;
    const u16* Vr = reinterpret_cast<const u16*>(V) + (size_t)job * 524288
                    + (size_t)(bcol + br) * 1024 + (t & 1) * 16;
    int bg0 = (t & 1) * 2, bg1 = bg0 + 1;
    int bsw0 = (bg0 ^ ((br >> 1) & 3)) * 8;
    int bsw1 = (bg1 ^ ((br >> 1) & 3)) * 8;
    int rsw = (nib ^ ((cc >> 1) & 3)) * 8;       // swizzled read col

    f32x4 acc[4][4] = {};

    {
        u16x8 p8 = *reinterpret_cast<const u16x8*>(Pr);
        u16x8 v0 = *reinterpret_cast<const u16x8*>(Vr);
        u16x8 v1 = *reinterpret_cast<const u16x8*>(Vr + 8);
        float af = alf[0];
        bf16x8 pw;
#pragma unroll
        for (int j = 0; j < 8; ++j) pw[j] = (bf16)(b2f(p8[j]) * af);
        *reinterpret_cast<bf16x8*>(&ldsA[0][ar * 32 + asw]) = pw;
        *reinterpret_cast<u16x8*>(&ldsB[0][br * 32 + bsw0]) = v0;
        *reinterpret_cast<u16x8*>(&ldsB[0][br * 32 + bsw1]) = v1;
    }
    __syncthreads();

#pragma unroll
    for (int kt = 0; kt < 32; ++kt) {
        int cur = kt & 1;
        u16x8 p8, v0, v1;
        if (kt < 31) {                            // T14: issue loads early
            p8 = *reinterpret_cast<const u16x8*>(Pr + (kt + 1) * 32);
            v0 = *reinterpret_cast<const u16x8*>(Vr + (kt + 1) * 32);
            v1 = *reinterpret_cast<const u16x8*>(Vr + (kt + 1) * 32 + 8);
        }
        bf16x8 a[4], b[4];
#pragma unroll
        for (int mi = 0; mi < 4; ++mi)
            a[mi] = *reinterpret_cast<const bf16x8*>(
                &ldsA[cur][(wm * 64 + mi * 16 + cc) * 32 + rsw]);
#pragma unroll
        for (int ni = 0; ni < 4; ++ni)
            b[ni] = *reinterpret_cast<const bf16x8*>(
                &ldsB[cur][(wn * 64 + ni * 16 + cc) * 32 + rsw]);
        __builtin_amdgcn_s_setprio(1);
#pragma unroll
        for (int mi = 0; mi < 4; ++mi)
#pragma unroll
            for (int ni = 0; ni < 4; ++ni)
                acc[mi][ni] = __builtin_amdgcn_mfma_f32_16x16x32_bf16(
                    a[mi], b[ni], acc[mi][ni], 0, 0, 0);
        __builtin_amdgcn_s_setprio(0);
        if (kt < 31) {                            // write-late into other slot
            float af = alf[(kt + 1) >> 3];
            bf16x8 pw;
#pragma unroll
            for (int j = 0; j < 8; ++j) pw[j] = (bf16)(b2f(p8[j]) * af);
            *reinterpret_cast<bf16x8*>(&ldsA[cur ^ 1][ar * 32 + asw]) = pw;
            *reinterpret_cast<u16x8*>(&ldsB[cur ^ 1][br * 32 + bsw0]) = v0;
            *reinterpret_cast<u16x8*>(&ldsB[cur ^ 1][br * 32 + bsw1]) = v1;
        }
        __syncthreads();
    }

    bf16* Oj = O + (size_t)job * 524288;
#pragma unroll
    for (int mi = 0; mi < 4; ++mi) {
#pragma unroll
        for (int r = 0; r < 4; ++r) {
            int lr = wm * 64 + mi * 16 + nib * 4 + r;
            float linv = 1.0f / Ll[lr];
#pragma unroll
            for (int ni = 0; ni < 4; ++ni) {
                int gcol = bcol + wn * 64 + ni * 16 + cc;
                Oj[(size_t)(brow + lr) * 512 + gcol] = (bf16)(acc[mi][ni][r] * linv);
            }
        }
    }
}

extern "C" void kernel_launch(void* const* d_in, const int* in_sizes, int n_in,
                              void* d_out, int out_size, void* d_ws, size_t ws_size,
                              hipStream_t stream)
{
    const float* x   = (const float*)d_in[0];
    const float* y   = (const float*)d_in[1];
    const float* ns  = (const float*)d_in[2];
    const float* nb  = (const float*)d_in[3];
    const float* n1s = (const float*)d_in[4];
    const float* n1b = (const float*)d_in[5];
    const float* wq  = (const float*)d_in[6];
    const float* bq  = (const float*)d_in[7];
    const float* wk  = (const float*)d_in[8];
    const float* bk  = (const float*)d_in[9];
    const float* wv  = (const float*)d_in[10];
    const float* bv  = (const float*)d_in[11];
    const float* wp  = (const float*)d_in[12];
    const float* bp  = (const float*)d_in[13];
    float* out = (float*)d_out;

    char* ws = (char*)d_ws;
    bf16* wbf  = (bf16*)ws;                          // 2 MB weights bf16
    float* bpk = (float*)(ws + 2097152);             // 8 KB biases
    bf16* ynT = (bf16*)(ws + 2105344);               // [b][hw][c]
    bf16* hnT = ynT + 8388608;
    bf16* qT  = hnT + 8388608;
    bf16* kT  = qT  + 8388608;
    bf16* v   = kT  + 8388608;                       // [b][c][hw]
    float* stats = (float*)ynT;                      // ynT dead after q/k conv
    bf16* aoT = qT;                                  // qT dead after QK^T
    bf16* P   = (bf16*)(ws + 2105344 + 5ull * 16777216);   // 32 MB bf16

    const size_t sBC = (size_t)kHW * kC;
    const float scl = 0.044194173824159216f;         // 512^-0.5

    wconv_kernel<<<1024, 256, 0, stream>>>(wq, wk, wv, wp, bq, bk, bv, bp, wbf, bpk);
    gn2_kernel<<<1024, 256, 0, stream>>>(x, ns, nb, hnT, y, n1s, n1b, ynT);

    // q & k convs fused (jobs 0/1): out_T[i][o] = in_T[i][c]·W[o][c] + b[o]
    gemm256<2, false, bf16, false, 2, 64><<<256, 512, 0, stream>>>(
        ynT, 8388608, 512, wbf, 262144, 512, qT, 8388608, 512,
        bpk, 512, nullptr, 0, 1.f, nullptr);
    // v conv per batch: v[o][n] = wv[o][c]·hnT[n][c] + bv[o]
    gemm128<1, false, bf16, 4, 4><<<256, 512, 0, stream>>>(
        wbf + 2 * 262144, 0, 512, hnT, sBC, 512, v, sBC, 1024,
        bpk + 1024, 0, nullptr, 0);
    // QK^T -> P_local bf16 + (M,L) stats per (row, bx)
    gemm256<0, false, bf16, true, 4, 4><<<256, 512, 0, stream>>>(
        qT, sBC, 512, kT, sBC, 512, P, 1048576, 1024,
        bpk, 0, nullptr, 0, scl, stats);
    // fused softmax-finish + PV -> aoT [b][hw][c]
    pv_gemm<<<256, 512, 0, stream>>>(P, stats, v, aoT);
    // proj + bias + residual
    gemm128<1, true, float, 4, 4><<<256, 512, 0, stream>>>(
        wbf + 3 * 262144, 0, 512, aoT, sBC, 512, out, sBC, 1024,
        bpk + 1536, 0, x, sBC);
}